// Round 12
// baseline (1388.470 us; speedup 1.0000x reference)
//
#include <hip/hip_runtime.h>
#include <math.h>

// Problem constants (fixed by the reference)
#define NN 50000          // nodes
#define NE 800000         // edges
#define NE2 (NE + NN)     // edges + self loops = 850000
#define INC 64            // in channels
#define EDD 16            // edge dim
#define NH 4              // heads
#define CC 64             // per-head channels
#define HC 256            // H*C
#define NG 2048           // graphs
#define SLOPE 0.2f

typedef float v2f __attribute__((ext_vector_type(2)));
typedef float v4f __attribute__((ext_vector_type(4)));

#define RFL(x) __builtin_amdgcn_readfirstlane(x)

// ---------------- DPP wave-64 sum (VALU pipe, no DS traffic) ----------------
template <int CTRL, int RM>
__device__ __forceinline__ float dpp_add(float x) {
  int t = __builtin_amdgcn_update_dpp(0, __builtin_bit_cast(int, x),
                                      CTRL, RM, 0xF, false);
  return x + __builtin_bit_cast(float, t);
}
__device__ __forceinline__ float wave_sum_bcast(float x) {
  x = dpp_add<0x111, 0xF>(x);   // row_shr:1
  x = dpp_add<0x112, 0xF>(x);   // row_shr:2
  x = dpp_add<0x114, 0xF>(x);   // row_shr:4
  x = dpp_add<0x118, 0xF>(x);   // row_shr:8  -> lane15/31/47/63 = row sums
  x = dpp_add<0x142, 0xA>(x);   // row_bcast:15 -> lane31/63 = 2-row sums
  x = dpp_add<0x143, 0xC>(x);   // row_bcast:31 -> lane63 = full sum
  return __builtin_bit_cast(float,
      __builtin_amdgcn_readlane(__builtin_bit_cast(int, x), 63));
}

// ---------------- mean edge attr ----------------
__global__ void ea_sum_kernel(const float* __restrict__ ea, float* __restrict__ meansum) {
  __shared__ float part[16];
  if (threadIdx.x < 16) part[threadIdx.x] = 0.f;
  __syncthreads();
  size_t stride = (size_t)gridDim.x * blockDim.x;          // multiple of 16
  size_t i = (size_t)blockIdx.x * blockDim.x + threadIdx.x;
  int cls = (int)(i & 15);                                  // constant along loop
  float s = 0.f;
  const size_t total = (size_t)NE * EDD;
  for (; i < total; i += stride) s += ea[i];
  atomicAdd(&part[cls], s);
  __syncthreads();
  if (threadIdx.x < 16) atomicAdd(&meansum[threadIdx.x], part[threadIdx.x]);
}

__global__ void ea_div_kernel(const float* __restrict__ meansum, float* __restrict__ meanea) {
  if (threadIdx.x < 16) meanea[threadIdx.x] = meansum[threadIdx.x] * (1.0f / NE);
}

// ---------------- CSR build (group edges by dst) ----------------
__global__ void count_dst_kernel(const int* __restrict__ ei, int* __restrict__ counts) {
  int e = blockIdx.x * blockDim.x + threadIdx.x;
  if (e >= NE2) return;
  int d = (e < NE) ? ei[NE + e] : (e - NE);
  atomicAdd(&counts[d], 1);
}

// 3-phase exclusive scan over n counts (n <= 256*256)
__global__ void scan_partial_kernel(const int* __restrict__ counts, int n,
                                    int* __restrict__ excl, int* __restrict__ btot) {
  int b = blockIdx.x;
  int i = b * 256 + threadIdx.x;
  int v = (i < n) ? counts[i] : 0;
  int lane = threadIdx.x & 63;
  int incl = v;
#pragma unroll
  for (int off = 1; off < 64; off <<= 1) {
    int t = __shfl_up(incl, off, 64);
    if (lane >= off) incl += t;
  }
  __shared__ int wtot[4];
  int w = threadIdx.x >> 6;
  if (lane == 63) wtot[w] = incl;
  __syncthreads();
  int woff = 0;
#pragma unroll
  for (int k = 0; k < 4; ++k) woff += (k < w) ? wtot[k] : 0;
  incl += woff;
  if (i < n) excl[i] = incl - v;
  if (threadIdx.x == 255) btot[b] = incl;
}

__global__ void scan_btot_kernel(int* __restrict__ btot, int nb, int* __restrict__ totp) {
  __shared__ int buf[256];
  int v = (threadIdx.x < nb) ? btot[threadIdx.x] : 0;
  buf[threadIdx.x] = v;
  __syncthreads();
  for (int off = 1; off < 256; off <<= 1) {
    int t = (threadIdx.x >= off) ? buf[threadIdx.x - off] : 0;
    __syncthreads();
    buf[threadIdx.x] += t;
    __syncthreads();
  }
  if (threadIdx.x < nb) btot[threadIdx.x] = buf[threadIdx.x] - v;  // exclusive
  if (threadIdx.x == 0) *totp = buf[nb - 1];                       // grand total
}

__global__ void scan_add_kernel(int* __restrict__ excl, int n, const int* __restrict__ btot) {
  int i = blockIdx.x * 256 + threadIdx.x;
  if (i < n) excl[i] += btot[blockIdx.x];
}

__global__ void fill_kernel(const int* __restrict__ ei, const int* __restrict__ row_ptr,
                            int* __restrict__ cursor, int2* __restrict__ edg) {
  int e = blockIdx.x * blockDim.x + threadIdx.x;
  if (e >= NE2) return;
  int d, s;
  if (e < NE) { d = ei[NE + e]; s = ei[e]; }
  else        { d = e - NE;     s = d;     }
  int pos = row_ptr[d] + atomicAdd(&cursor[d], 1);
  edg[pos] = make_int2(e, s);
}

// ---------------- f32 GEMM: [xl|xr] = X @ [Wl|Wr], fused ----------------
// BM=128, BN=128, BK=16, 256 threads, 8x8 per-thread tile.
// grid.y: 0,1 -> Wl cols 0/128 into Yl; 2,3 -> Wr cols 0/128 into Yr.
__global__ __launch_bounds__(256, 2) void gemm2_kernel(
    const float* __restrict__ X,
    const float* __restrict__ Wl, const float* __restrict__ Wr,
    float* __restrict__ Yl, float* __restrict__ Yr, int n, int K) {
  __shared__ float Xs[16][128];
  __shared__ float Ws[16][128];
  const int tid = threadIdx.x;
  const int row0 = blockIdx.x * 128;
  const int quad = blockIdx.y;                 // 0..3
  const float* W = (quad < 2) ? Wl : Wr;
  float* Y = (quad < 2) ? Yl : Yr;
  const int col0 = (quad & 1) * 128;
  const int tr = tid >> 4, tc = tid & 15;      // 16x16 thread grid
  float acc[8][8] = {};
  for (int k0 = 0; k0 < K; k0 += 16) {
    // stage X tile transposed -> Xs[k][m]; 128 rows x 16k, 8 floats/thread
    {
      int m = tid >> 1;                        // 0..127
      int kq = (tid & 1) * 8;                  // 0 or 8
      float4 v0 = make_float4(0.f, 0.f, 0.f, 0.f);
      float4 v1 = make_float4(0.f, 0.f, 0.f, 0.f);
      int r = row0 + m;
      if (r < n) {
        v0 = *(const float4*)(X + (size_t)r * K + k0 + kq);
        v1 = *(const float4*)(X + (size_t)r * K + k0 + kq + 4);
      }
      Xs[kq + 0][m] = v0.x; Xs[kq + 1][m] = v0.y;
      Xs[kq + 2][m] = v0.z; Xs[kq + 3][m] = v0.w;
      Xs[kq + 4][m] = v1.x; Xs[kq + 5][m] = v1.y;
      Xs[kq + 6][m] = v1.z; Xs[kq + 7][m] = v1.w;
    }
    // stage W tile: Ws[k][col]; 16k x 128 cols, 8 floats/thread
    {
      int kk = tid >> 4;                       // 0..15
      int nq = (tid & 15) * 8;                 // 0..120
      float4 w0 = *(const float4*)(W + (size_t)(k0 + kk) * HC + col0 + nq);
      float4 w1 = *(const float4*)(W + (size_t)(k0 + kk) * HC + col0 + nq + 4);
      *(float4*)(&Ws[kk][nq])     = w0;
      *(float4*)(&Ws[kk][nq + 4]) = w1;
    }
    __syncthreads();
#pragma unroll
    for (int k = 0; k < 16; ++k) {
      float a[8], b[8];
      *(float4*)(a)     = *(const float4*)(&Xs[k][tr * 8]);
      *(float4*)(a + 4) = *(const float4*)(&Xs[k][tr * 8 + 4]);
      *(float4*)(b)     = *(const float4*)(&Ws[k][tc * 8]);
      *(float4*)(b + 4) = *(const float4*)(&Ws[k][tc * 8 + 4]);
#pragma unroll
      for (int i = 0; i < 8; ++i)
#pragma unroll
        for (int jj = 0; jj < 8; ++jj) acc[i][jj] += a[i] * b[jj];
    }
    __syncthreads();
  }
#pragma unroll
  for (int i = 0; i < 8; ++i) {
    int r = row0 + tr * 8 + i;
    if (r < n) {
      *(float4*)(Y + (size_t)r * HC + col0 + tc * 8) =
          make_float4(acc[i][0], acc[i][1], acc[i][2], acc[i][3]);
      *(float4*)(Y + (size_t)r * HC + col0 + tc * 8 + 4) =
          make_float4(acc[i][4], acc[i][5], acc[i][6], acc[i][7]);
    }
  }
}

// ---------------- fused edge score + softmax + aggregate ----------------
// r11 structure, but ea row loads forced onto the VECTOR memory path
// (VGPR offset via asm) so they pipeline under vmcnt instead of serializing
// through the SGPR file. Two 4-edge half-batches bound live ea regs to 64.
__device__ __forceinline__ void load_ea4(const char* __restrict__ eab,
                                         int ex, v4f (&A)[4]) {
  unsigned eo = (unsigned)((ex < NE) ? ex : 0) << 6;   // clamp self-loops to row 0
  asm volatile("" : "+v"(eo));                         // force offset into VGPR
  const char* p = eab + eo;
  A[0] = *(const v4f*)(p);
  A[1] = *(const v4f*)(p + 16);
  A[2] = *(const v4f*)(p + 32);
  A[3] = *(const v4f*)(p + 48);
}

__device__ __forceinline__ float ee_from(const v4f (&A)[4], const v2f (&wreg)[8],
                                         int ex, float see) {
  v2f s = (v2f){A[0].x, A[0].y} * wreg[0] + (v2f){A[0].z, A[0].w} * wreg[1]
        + (v2f){A[1].x, A[1].y} * wreg[2] + (v2f){A[1].z, A[1].w} * wreg[3]
        + (v2f){A[2].x, A[2].y} * wreg[4] + (v2f){A[2].z, A[2].w} * wreg[5]
        + (v2f){A[3].x, A[3].y} * wreg[6] + (v2f){A[3].z, A[3].w} * wreg[7];
  return (ex < NE) ? (s.x + s.y) : see;
}

__global__ __launch_bounds__(256, 4) void edge_agg_kernel(
    const float* __restrict__ xl, const float* __restrict__ xr,
    const int* __restrict__ row_ptr, const int2* __restrict__ edg,
    const float* __restrict__ ea, const float* __restrict__ meanea,
    const float* __restrict__ We, const float* __restrict__ att,
    const float* __restrict__ bias, float* __restrict__ out) {
  const int lane = threadIdx.x & 63;
  const int head = threadIdx.x >> 6;          // 0..3
  const int node = blockIdx.x;
  const unsigned c = (unsigned)head * CC + (unsigned)lane;   // channel 0..255

  v2f wreg[8];
#pragma unroll
  for (int d = 0; d < 8; ++d)
    wreg[d] = (v2f){We[(unsigned)(2 * d) * HC + c], We[(unsigned)(2 * d + 1) * HC + c]};
  const float attl = att[c] * 1.44269504088896340736f;   // fold log2(e)
  const float xrl  = xr[((unsigned)node << 8) + c];
  v2f seev = {0.f, 0.f};
#pragma unroll
  for (int d = 0; d < 8; ++d)
    seev += (v2f){meanea[2 * d], meanea[2 * d + 1]} * wreg[d];
  const float see = seev.x + seev.y;

  float den = 0.f, acc = 0.f;
  const int beg = row_ptr[node];
  const int end = row_ptr[node + 1];
  const char* eab = (const char*)ea;

  int j = beg;
  // ---- full 8-edge batches ----
  for (; j + 8 <= end; j += 8) {
    int2 E[8];
#pragma unroll
    for (int k = 0; k < 8; ++k) E[k] = edg[(unsigned)(j + k)];
    float X[8];
#pragma unroll
    for (int k = 0; k < 8; ++k) X[k] = xl[((unsigned)E[k].y << 8) + c];
    float q[8];
    // half-batch 0: edges 0..3
    {
      v4f A[4][4];
#pragma unroll
      for (int k = 0; k < 4; ++k) load_ea4(eab, E[k].x, A[k]);
#pragma unroll
      for (int k = 0; k < 4; ++k) {
        float ee = ee_from(A[k], wreg, E[k].x, see);
        float t = X[k] + xrl + ee;
        t = (t > 0.f) ? t : SLOPE * t;
        q[k] = t * attl;
      }
    }
    // half-batch 1: edges 4..7
    {
      v4f A[4][4];
#pragma unroll
      for (int k = 0; k < 4; ++k) load_ea4(eab, E[4 + k].x, A[k]);
#pragma unroll
      for (int k = 0; k < 4; ++k) {
        float ee = ee_from(A[k], wreg, E[4 + k].x, see);
        float t = X[4 + k] + xrl + ee;
        t = (t > 0.f) ? t : SLOPE * t;
        q[4 + k] = t * attl;
      }
    }
#pragma unroll
    for (int k = 0; k < 8; ++k) q[k] = wave_sum_bcast(q[k]);
#pragma unroll
    for (int k = 0; k < 8; ++k) {
      float w = exp2f(q[k]);
      den += w;
      acc = fmaf(w, X[k], acc);
    }
  }
  // ---- tail batch (clamped) ----
  if (j < end) {
    const int rem = end - j;                  // 1..7
    int2 E[8];
#pragma unroll
    for (int k = 0; k < 8; ++k) E[k] = edg[(unsigned)(j + (k < rem ? k : 0))];
    float X[8];
#pragma unroll
    for (int k = 0; k < 8; ++k) X[k] = xl[((unsigned)E[k].y << 8) + c];
    float q[8];
    {
      v4f A[4][4];
#pragma unroll
      for (int k = 0; k < 4; ++k) load_ea4(eab, E[k].x, A[k]);
#pragma unroll
      for (int k = 0; k < 4; ++k) {
        float ee = ee_from(A[k], wreg, E[k].x, see);
        float t = X[k] + xrl + ee;
        t = (t > 0.f) ? t : SLOPE * t;
        q[k] = t * attl;
      }
    }
    {
      v4f A[4][4];
#pragma unroll
      for (int k = 0; k < 4; ++k) load_ea4(eab, E[4 + k].x, A[k]);
#pragma unroll
      for (int k = 0; k < 4; ++k) {
        float ee = ee_from(A[k], wreg, E[4 + k].x, see);
        float t = X[4 + k] + xrl + ee;
        t = (t > 0.f) ? t : SLOPE * t;
        q[4 + k] = t * attl;
      }
    }
#pragma unroll
    for (int k = 0; k < 8; ++k) q[k] = wave_sum_bcast(q[k]);
#pragma unroll
    for (int k = 0; k < 8; ++k) {
      float w = (k < rem) ? exp2f(q[k]) : 0.f;
      den += w;
      acc = fmaf(w, X[k], acc);
    }
  }
  float o = fmaxf(acc / (den + 1e-16f) + bias[c], 0.f);   // fused ReLU
  out[((unsigned)node << 8) + c] = o;
}

// ---------------- graph ranges from sorted batch ----------------
__global__ void graph_bounds_kernel(const int* __restrict__ batch, int* __restrict__ gstart) {
  int i = blockIdx.x * blockDim.x + threadIdx.x;
  if (i >= NN) return;
  int b = batch[i];
  int prev = (i == 0) ? -1 : batch[i - 1];
  for (int g = prev + 1; g <= b; ++g) gstart[g] = i;
  if (i == NN - 1)
    for (int g = b + 1; g <= NG; ++g) gstart[g] = NN;
}

// ---------------- global mean pool: one wave per graph ----------------
__global__ void pool_kernel(const float* __restrict__ h2, const int* __restrict__ gstart,
                            float* __restrict__ pooled) {
  int lane = threadIdx.x & 63;
  int g = blockIdx.x * 4 + (threadIdx.x >> 6);
  if (g >= NG) return;
  int s = RFL(gstart[g]), e = RFL(gstart[g + 1]);
  float sx = 0.f, sy = 0.f, sz = 0.f, sw = 0.f;
  for (int i = s; i < e; ++i) {
    float4 v = *(const float4*)(h2 + (size_t)i * HC + lane * 4);
    sx += v.x; sy += v.y; sz += v.z; sw += v.w;
  }
  float inv = 1.f / fmaxf((float)(e - s), 1.f);
  *(float4*)(pooled + (size_t)g * HC + lane * 4) =
      make_float4(sx * inv, sy * inv, sz * inv, sw * inv);
}

// ---------------- final linear: out[g] = pooled_mean . Wf + bf ----------------
__global__ void final_kernel(const float* __restrict__ pooled,
                             const float* __restrict__ Wf, const float* __restrict__ bf,
                             float* __restrict__ out) {
  int lane = threadIdx.x & 63;
  int g = blockIdx.x * (blockDim.x >> 6) + (threadIdx.x >> 6);
  if (g >= NG) return;
  float4 p = *(const float4*)(pooled + (size_t)g * HC + lane * 4);
  float4 w = *(const float4*)(Wf + lane * 4);
  float s = p.x * w.x + p.y * w.y + p.z * w.z + p.w * w.w;
  s += __shfl_xor(s, 1, 64);  s += __shfl_xor(s, 2, 64);
  s += __shfl_xor(s, 4, 64);  s += __shfl_xor(s, 8, 64);
  s += __shfl_xor(s, 16, 64); s += __shfl_xor(s, 32, 64);
  if (lane == 0) out[g] = s + bf[0];
}

extern "C" void kernel_launch(void* const* d_in, const int* in_sizes, int n_in,
                              void* d_out, int out_size, void* d_ws, size_t ws_size,
                              hipStream_t stream) {
  const float* x    = (const float*)d_in[0];
  const int*   ei   = (const int*)d_in[1];   // [2,E]: src row 0, dst row 1
  const int*   batch= (const int*)d_in[2];
  const float* ea   = (const float*)d_in[3];
  const float* Wl1  = (const float*)d_in[4];
  const float* Wr1  = (const float*)d_in[5];
  const float* We1  = (const float*)d_in[6];
  const float* att1 = (const float*)d_in[7];
  const float* b1   = (const float*)d_in[8];
  const float* Wl2  = (const float*)d_in[9];
  const float* Wr2  = (const float*)d_in[10];
  const float* We2  = (const float*)d_in[11];
  const float* att2 = (const float*)d_in[12];
  const float* b2   = (const float*)d_in[13];
  const float* Wf   = (const float*)d_in[14];
  const float* bf   = (const float*)d_in[15];
  float* out = (float*)d_out;

  // workspace layout
  float* xl      = (float*)d_ws;               // N*256
  float* xr      = xl + (size_t)NN * HC;       // N*256
  float* h1      = xr + (size_t)NN * HC;       // N*256
  float* pooled  = h1 + (size_t)NN * HC;       // G*256
  float* meansum = pooled + (size_t)NG * HC;   // 16
  float* meanea  = meansum + 16;               // 16
  int* counts  = (int*)(meanea + 16);          // N
  int* row_ptr = counts + NN;                  // N+1
  int* btot    = row_ptr + NN + 1;             // 256
  int* gstart  = btot + 256;                   // G+1
  int2* edg    = (int2*)(gstart + NG + 1);     // E2 (8B aligned: offset even)

  const int NB = (NN + 255) / 256;             // 196 scan blocks

  hipMemsetAsync(counts, 0, NN * sizeof(int), stream);
  hipMemsetAsync(meansum, 0, 16 * sizeof(float), stream);

  ea_sum_kernel<<<1024, 256, 0, stream>>>(ea, meansum);
  ea_div_kernel<<<1, 16, 0, stream>>>(meansum, meanea);

  count_dst_kernel<<<(NE2 + 255) / 256, 256, 0, stream>>>(ei, counts);
  scan_partial_kernel<<<NB, 256, 0, stream>>>(counts, NN, row_ptr, btot);
  scan_btot_kernel<<<1, 256, 0, stream>>>(btot, NB, row_ptr + NN);
  scan_add_kernel<<<NB, 256, 0, stream>>>(row_ptr, NN, btot);
  hipMemsetAsync(counts, 0, NN * sizeof(int), stream);
  fill_kernel<<<(NE2 + 255) / 256, 256, 0, stream>>>(ei, row_ptr, counts, edg);
  graph_bounds_kernel<<<(NN + 255) / 256, 256, 0, stream>>>(batch, gstart);

  dim3 ggrid((NN + 127) / 128, 4);
  // layer 1 (fused Wl|Wr GEMM)
  gemm2_kernel<<<ggrid, 256, 0, stream>>>(x, Wl1, Wr1, xl, xr, NN, INC);
  edge_agg_kernel<<<NN, 256, 0, stream>>>(xl, xr, row_ptr, edg, ea, meanea,
                                          We1, att1, b1, h1);
  // layer 2 (reuse xl/xr buffers)
  gemm2_kernel<<<ggrid, 256, 0, stream>>>(h1, Wl2, Wr2, xl, xr, NN, HC);
  edge_agg_kernel<<<NN, 256, 0, stream>>>(xl, xr, row_ptr, edg, ea, meanea,
                                          We2, att2, b2, h1);
  // pooling + ffn
  pool_kernel<<<(NG + 3) / 4, 256, 0, stream>>>(h1, gstart, pooled);
  final_kernel<<<(NG + 3) / 4, 256, 0, stream>>>(pooled, Wf, bf, out);
}

// Round 13
// 903.101 us; speedup vs baseline: 1.5374x; 1.5374x over previous
//
#include <hip/hip_runtime.h>
#include <math.h>

// Problem constants (fixed by the reference)
#define NN 50000          // nodes
#define NE 800000         // edges
#define NE2 (NE + NN)     // edges + self loops = 850000
#define INC 64            // in channels
#define EDD 16            // edge dim
#define NH 4              // heads
#define CC 64             // per-head channels
#define HC 256            // H*C
#define NG 2048           // graphs
#define SLOPE 0.2f

typedef float v2f __attribute__((ext_vector_type(2)));
typedef float v4f __attribute__((ext_vector_type(4)));

#define RFL(x) __builtin_amdgcn_readfirstlane(x)

// ---------------- DPP wave-64 sum (VALU pipe, no DS traffic) ----------------
template <int CTRL, int RM>
__device__ __forceinline__ float dpp_add(float x) {
  int t = __builtin_amdgcn_update_dpp(0, __builtin_bit_cast(int, x),
                                      CTRL, RM, 0xF, false);
  return x + __builtin_bit_cast(float, t);
}
__device__ __forceinline__ float wave_sum_bcast(float x) {
  x = dpp_add<0x111, 0xF>(x);   // row_shr:1
  x = dpp_add<0x112, 0xF>(x);   // row_shr:2
  x = dpp_add<0x114, 0xF>(x);   // row_shr:4
  x = dpp_add<0x118, 0xF>(x);   // row_shr:8  -> lane15/31/47/63 = row sums
  x = dpp_add<0x142, 0xA>(x);   // row_bcast:15 -> lane31/63 = 2-row sums
  x = dpp_add<0x143, 0xC>(x);   // row_bcast:31 -> lane63 = full sum
  return __builtin_bit_cast(float,
      __builtin_amdgcn_readlane(__builtin_bit_cast(int, x), 63));
}

// ---------------- mean edge attr ----------------
__global__ void ea_sum_kernel(const float* __restrict__ ea, float* __restrict__ meansum) {
  __shared__ float part[16];
  if (threadIdx.x < 16) part[threadIdx.x] = 0.f;
  __syncthreads();
  size_t stride = (size_t)gridDim.x * blockDim.x;          // multiple of 16
  size_t i = (size_t)blockIdx.x * blockDim.x + threadIdx.x;
  int cls = (int)(i & 15);                                  // constant along loop
  float s = 0.f;
  const size_t total = (size_t)NE * EDD;
  for (; i < total; i += stride) s += ea[i];
  atomicAdd(&part[cls], s);
  __syncthreads();
  if (threadIdx.x < 16) atomicAdd(&meansum[threadIdx.x], part[threadIdx.x]);
}

__global__ void ea_div_kernel(const float* __restrict__ meansum, float* __restrict__ meanea) {
  if (threadIdx.x < 16) meanea[threadIdx.x] = meansum[threadIdx.x] * (1.0f / NE);
}

// ---------------- CSR build (group edges by dst) ----------------
__global__ void count_dst_kernel(const int* __restrict__ ei, int* __restrict__ counts) {
  int e = blockIdx.x * blockDim.x + threadIdx.x;
  if (e >= NE2) return;
  int d = (e < NE) ? ei[NE + e] : (e - NE);
  atomicAdd(&counts[d], 1);
}

// 3-phase exclusive scan over n counts (n <= 256*256)
__global__ void scan_partial_kernel(const int* __restrict__ counts, int n,
                                    int* __restrict__ excl, int* __restrict__ btot) {
  int b = blockIdx.x;
  int i = b * 256 + threadIdx.x;
  int v = (i < n) ? counts[i] : 0;
  int lane = threadIdx.x & 63;
  int incl = v;
#pragma unroll
  for (int off = 1; off < 64; off <<= 1) {
    int t = __shfl_up(incl, off, 64);
    if (lane >= off) incl += t;
  }
  __shared__ int wtot[4];
  int w = threadIdx.x >> 6;
  if (lane == 63) wtot[w] = incl;
  __syncthreads();
  int woff = 0;
#pragma unroll
  for (int k = 0; k < 4; ++k) woff += (k < w) ? wtot[k] : 0;
  incl += woff;
  if (i < n) excl[i] = incl - v;
  if (threadIdx.x == 255) btot[b] = incl;
}

__global__ void scan_btot_kernel(int* __restrict__ btot, int nb, int* __restrict__ totp) {
  __shared__ int buf[256];
  int v = (threadIdx.x < nb) ? btot[threadIdx.x] : 0;
  buf[threadIdx.x] = v;
  __syncthreads();
  for (int off = 1; off < 256; off <<= 1) {
    int t = (threadIdx.x >= off) ? buf[threadIdx.x - off] : 0;
    __syncthreads();
    buf[threadIdx.x] += t;
    __syncthreads();
  }
  if (threadIdx.x < nb) btot[threadIdx.x] = buf[threadIdx.x] - v;  // exclusive
  if (threadIdx.x == 0) *totp = buf[nb - 1];                       // grand total
}

__global__ void scan_add_kernel(int* __restrict__ excl, int n, const int* __restrict__ btot) {
  int i = blockIdx.x * 256 + threadIdx.x;
  if (i < n) excl[i] += btot[blockIdx.x];
}

__global__ void fill_kernel(const int* __restrict__ ei, const int* __restrict__ row_ptr,
                            int* __restrict__ cursor, int2* __restrict__ edg) {
  int e = blockIdx.x * blockDim.x + threadIdx.x;
  if (e >= NE2) return;
  int d, s;
  if (e < NE) { d = ei[NE + e]; s = ei[e]; }
  else        { d = e - NE;     s = d;     }
  int pos = row_ptr[d] + atomicAdd(&cursor[d], 1);
  edg[pos] = make_int2(e, s);
}

// ---------------- f32 GEMM: [xl|xr] = X @ [Wl|Wr], fused ----------------
// BM=128, BN=128, BK=16, 256 threads, 8x8 per-thread tile.
// grid.y: 0,1 -> Wl cols 0/128 into Yl; 2,3 -> Wr cols 0/128 into Yr.
__global__ __launch_bounds__(256, 2) void gemm2_kernel(
    const float* __restrict__ X,
    const float* __restrict__ Wl, const float* __restrict__ Wr,
    float* __restrict__ Yl, float* __restrict__ Yr, int n, int K) {
  __shared__ float Xs[16][128];
  __shared__ float Ws[16][128];
  const int tid = threadIdx.x;
  const int row0 = blockIdx.x * 128;
  const int quad = blockIdx.y;                 // 0..3
  const float* W = (quad < 2) ? Wl : Wr;
  float* Y = (quad < 2) ? Yl : Yr;
  const int col0 = (quad & 1) * 128;
  const int tr = tid >> 4, tc = tid & 15;      // 16x16 thread grid
  float acc[8][8] = {};
  for (int k0 = 0; k0 < K; k0 += 16) {
    // stage X tile transposed -> Xs[k][m]; 128 rows x 16k, 8 floats/thread
    {
      int m = tid >> 1;                        // 0..127
      int kq = (tid & 1) * 8;                  // 0 or 8
      float4 v0 = make_float4(0.f, 0.f, 0.f, 0.f);
      float4 v1 = make_float4(0.f, 0.f, 0.f, 0.f);
      int r = row0 + m;
      if (r < n) {
        v0 = *(const float4*)(X + (size_t)r * K + k0 + kq);
        v1 = *(const float4*)(X + (size_t)r * K + k0 + kq + 4);
      }
      Xs[kq + 0][m] = v0.x; Xs[kq + 1][m] = v0.y;
      Xs[kq + 2][m] = v0.z; Xs[kq + 3][m] = v0.w;
      Xs[kq + 4][m] = v1.x; Xs[kq + 5][m] = v1.y;
      Xs[kq + 6][m] = v1.z; Xs[kq + 7][m] = v1.w;
    }
    // stage W tile: Ws[k][col]; 16k x 128 cols, 8 floats/thread
    {
      int kk = tid >> 4;                       // 0..15
      int nq = (tid & 15) * 8;                 // 0..120
      float4 w0 = *(const float4*)(W + (size_t)(k0 + kk) * HC + col0 + nq);
      float4 w1 = *(const float4*)(W + (size_t)(k0 + kk) * HC + col0 + nq + 4);
      *(float4*)(&Ws[kk][nq])     = w0;
      *(float4*)(&Ws[kk][nq + 4]) = w1;
    }
    __syncthreads();
#pragma unroll
    for (int k = 0; k < 16; ++k) {
      float a[8], b[8];
      *(float4*)(a)     = *(const float4*)(&Xs[k][tr * 8]);
      *(float4*)(a + 4) = *(const float4*)(&Xs[k][tr * 8 + 4]);
      *(float4*)(b)     = *(const float4*)(&Ws[k][tc * 8]);
      *(float4*)(b + 4) = *(const float4*)(&Ws[k][tc * 8 + 4]);
#pragma unroll
      for (int i = 0; i < 8; ++i)
#pragma unroll
        for (int jj = 0; jj < 8; ++jj) acc[i][jj] += a[i] * b[jj];
    }
    __syncthreads();
  }
#pragma unroll
  for (int i = 0; i < 8; ++i) {
    int r = row0 + tr * 8 + i;
    if (r < n) {
      *(float4*)(Y + (size_t)r * HC + col0 + tc * 8) =
          make_float4(acc[i][0], acc[i][1], acc[i][2], acc[i][3]);
      *(float4*)(Y + (size_t)r * HC + col0 + tc * 8 + 4) =
          make_float4(acc[i][4], acc[i][5], acc[i][6], acc[i][7]);
    }
  }
}

// ---------------- fused edge score + softmax + aggregate ----------------
// r11 structure (one wave per (node, head), lane owns one channel, DPP
// reduction, scalar ea loads) with EXACT tails: batch body templated over B
// and remainder processed as 4/2/1 sub-batches -> zero clamped slots.
template <int B>
__device__ __forceinline__ void edge_batch(
    int j, const int2* __restrict__ edg, const float* __restrict__ xl,
    const float* __restrict__ ea, const v2f (&wreg)[8],
    float see, float xrl, float attl, unsigned c,
    float& den, float& acc) {
  int2 E[B];
#pragma unroll
  for (int k = 0; k < B; ++k) E[k] = edg[(unsigned)(j + k)];
  float X[B];
#pragma unroll
  for (int k = 0; k < B; ++k) X[k] = xl[((unsigned)E[k].y << 8) + c];
  float q[B];
#pragma unroll
  for (int k = 0; k < B; ++k) {
    float ee;
    if (E[k].x < NE) {
      const float* eap = ea + ((size_t)((unsigned)E[k].x << 4));
      v4f a0 = *(const v4f*)(eap);
      v4f a1 = *(const v4f*)(eap + 4);
      v4f a2 = *(const v4f*)(eap + 8);
      v4f a3 = *(const v4f*)(eap + 12);
      v2f s = (v2f){a0.x, a0.y} * wreg[0] + (v2f){a0.z, a0.w} * wreg[1]
            + (v2f){a1.x, a1.y} * wreg[2] + (v2f){a1.z, a1.w} * wreg[3]
            + (v2f){a2.x, a2.y} * wreg[4] + (v2f){a2.z, a2.w} * wreg[5]
            + (v2f){a3.x, a3.y} * wreg[6] + (v2f){a3.z, a3.w} * wreg[7];
      ee = s.x + s.y;
    } else {
      ee = see;
    }
    float t = X[k] + xrl + ee;
    t = (t > 0.f) ? t : SLOPE * t;
    q[k] = t * attl;
  }
#pragma unroll
  for (int k = 0; k < B; ++k) q[k] = wave_sum_bcast(q[k]);
#pragma unroll
  for (int k = 0; k < B; ++k) {
    float w = exp2f(q[k]);
    den += w;
    acc = fmaf(w, X[k], acc);
  }
}

__global__ __launch_bounds__(256, 4) void edge_agg_kernel(
    const float* __restrict__ xl, const float* __restrict__ xr,
    const int* __restrict__ row_ptr, const int2* __restrict__ edg,
    const float* __restrict__ ea, const float* __restrict__ meanea,
    const float* __restrict__ We, const float* __restrict__ att,
    const float* __restrict__ bias, float* __restrict__ out) {
  const int lane = threadIdx.x & 63;
  const int head = threadIdx.x >> 6;          // 0..3
  const int node = blockIdx.x;
  const unsigned c = (unsigned)head * CC + (unsigned)lane;   // channel 0..255

  v2f wreg[8];
#pragma unroll
  for (int d = 0; d < 8; ++d)
    wreg[d] = (v2f){We[(unsigned)(2 * d) * HC + c], We[(unsigned)(2 * d + 1) * HC + c]};
  const float attl = att[c] * 1.44269504088896340736f;   // fold log2(e)
  const float xrl  = xr[((unsigned)node << 8) + c];
  v2f seev = {0.f, 0.f};
#pragma unroll
  for (int d = 0; d < 8; ++d)
    seev += (v2f){meanea[2 * d], meanea[2 * d + 1]} * wreg[d];
  const float see = seev.x + seev.y;

  float den = 0.f, acc = 0.f;
  const int beg = row_ptr[node];
  const int end = row_ptr[node + 1];

  int j = beg;
  for (; j + 8 <= end; j += 8)
    edge_batch<8>(j, edg, xl, ea, wreg, see, xrl, attl, c, den, acc);
  const int rem = end - j;                    // 0..7, wave-uniform
  if (rem & 4) {
    edge_batch<4>(j, edg, xl, ea, wreg, see, xrl, attl, c, den, acc);
    j += 4;
  }
  if (rem & 2) {
    edge_batch<2>(j, edg, xl, ea, wreg, see, xrl, attl, c, den, acc);
    j += 2;
  }
  if (rem & 1) {
    edge_batch<1>(j, edg, xl, ea, wreg, see, xrl, attl, c, den, acc);
  }

  float o = fmaxf(acc / (den + 1e-16f) + bias[c], 0.f);   // fused ReLU
  out[((unsigned)node << 8) + c] = o;
}

// ---------------- graph ranges from sorted batch ----------------
__global__ void graph_bounds_kernel(const int* __restrict__ batch, int* __restrict__ gstart) {
  int i = blockIdx.x * blockDim.x + threadIdx.x;
  if (i >= NN) return;
  int b = batch[i];
  int prev = (i == 0) ? -1 : batch[i - 1];
  for (int g = prev + 1; g <= b; ++g) gstart[g] = i;
  if (i == NN - 1)
    for (int g = b + 1; g <= NG; ++g) gstart[g] = NN;
}

// ---------------- global mean pool: one wave per graph ----------------
__global__ void pool_kernel(const float* __restrict__ h2, const int* __restrict__ gstart,
                            float* __restrict__ pooled) {
  int lane = threadIdx.x & 63;
  int g = blockIdx.x * 4 + (threadIdx.x >> 6);
  if (g >= NG) return;
  int s = RFL(gstart[g]), e = RFL(gstart[g + 1]);
  float sx = 0.f, sy = 0.f, sz = 0.f, sw = 0.f;
  for (int i = s; i < e; ++i) {
    float4 v = *(const float4*)(h2 + (size_t)i * HC + lane * 4);
    sx += v.x; sy += v.y; sz += v.z; sw += v.w;
  }
  float inv = 1.f / fmaxf((float)(e - s), 1.f);
  *(float4*)(pooled + (size_t)g * HC + lane * 4) =
      make_float4(sx * inv, sy * inv, sz * inv, sw * inv);
}

// ---------------- final linear: out[g] = pooled_mean . Wf + bf ----------------
__global__ void final_kernel(const float* __restrict__ pooled,
                             const float* __restrict__ Wf, const float* __restrict__ bf,
                             float* __restrict__ out) {
  int lane = threadIdx.x & 63;
  int g = blockIdx.x * (blockDim.x >> 6) + (threadIdx.x >> 6);
  if (g >= NG) return;
  float4 p = *(const float4*)(pooled + (size_t)g * HC + lane * 4);
  float4 w = *(const float4*)(Wf + lane * 4);
  float s = p.x * w.x + p.y * w.y + p.z * w.z + p.w * w.w;
  s += __shfl_xor(s, 1, 64);  s += __shfl_xor(s, 2, 64);
  s += __shfl_xor(s, 4, 64);  s += __shfl_xor(s, 8, 64);
  s += __shfl_xor(s, 16, 64); s += __shfl_xor(s, 32, 64);
  if (lane == 0) out[g] = s + bf[0];
}

extern "C" void kernel_launch(void* const* d_in, const int* in_sizes, int n_in,
                              void* d_out, int out_size, void* d_ws, size_t ws_size,
                              hipStream_t stream) {
  const float* x    = (const float*)d_in[0];
  const int*   ei   = (const int*)d_in[1];   // [2,E]: src row 0, dst row 1
  const int*   batch= (const int*)d_in[2];
  const float* ea   = (const float*)d_in[3];
  const float* Wl1  = (const float*)d_in[4];
  const float* Wr1  = (const float*)d_in[5];
  const float* We1  = (const float*)d_in[6];
  const float* att1 = (const float*)d_in[7];
  const float* b1   = (const float*)d_in[8];
  const float* Wl2  = (const float*)d_in[9];
  const float* Wr2  = (const float*)d_in[10];
  const float* We2  = (const float*)d_in[11];
  const float* att2 = (const float*)d_in[12];
  const float* b2   = (const float*)d_in[13];
  const float* Wf   = (const float*)d_in[14];
  const float* bf   = (const float*)d_in[15];
  float* out = (float*)d_out;

  // workspace layout
  float* xl      = (float*)d_ws;               // N*256
  float* xr      = xl + (size_t)NN * HC;       // N*256
  float* h1      = xr + (size_t)NN * HC;       // N*256
  float* pooled  = h1 + (size_t)NN * HC;       // G*256
  float* meansum = pooled + (size_t)NG * HC;   // 16
  float* meanea  = meansum + 16;               // 16
  int* counts  = (int*)(meanea + 16);          // N
  int* row_ptr = counts + NN;                  // N+1
  int* btot    = row_ptr + NN + 1;             // 256
  int* gstart  = btot + 256;                   // G+1
  int2* edg    = (int2*)(gstart + NG + 1);     // E2 (8B aligned: offset even)

  const int NB = (NN + 255) / 256;             // 196 scan blocks

  hipMemsetAsync(counts, 0, NN * sizeof(int), stream);
  hipMemsetAsync(meansum, 0, 16 * sizeof(float), stream);

  ea_sum_kernel<<<1024, 256, 0, stream>>>(ea, meansum);
  ea_div_kernel<<<1, 16, 0, stream>>>(meansum, meanea);

  count_dst_kernel<<<(NE2 + 255) / 256, 256, 0, stream>>>(ei, counts);
  scan_partial_kernel<<<NB, 256, 0, stream>>>(counts, NN, row_ptr, btot);
  scan_btot_kernel<<<1, 256, 0, stream>>>(btot, NB, row_ptr + NN);
  scan_add_kernel<<<NB, 256, 0, stream>>>(row_ptr, NN, btot);
  hipMemsetAsync(counts, 0, NN * sizeof(int), stream);
  fill_kernel<<<(NE2 + 255) / 256, 256, 0, stream>>>(ei, row_ptr, counts, edg);
  graph_bounds_kernel<<<(NN + 255) / 256, 256, 0, stream>>>(batch, gstart);

  dim3 ggrid((NN + 127) / 128, 4);
  // layer 1 (fused Wl|Wr GEMM)
  gemm2_kernel<<<ggrid, 256, 0, stream>>>(x, Wl1, Wr1, xl, xr, NN, INC);
  edge_agg_kernel<<<NN, 256, 0, stream>>>(xl, xr, row_ptr, edg, ea, meanea,
                                          We1, att1, b1, h1);
  // layer 2 (reuse xl/xr buffers)
  gemm2_kernel<<<ggrid, 256, 0, stream>>>(h1, Wl2, Wr2, xl, xr, NN, HC);
  edge_agg_kernel<<<NN, 256, 0, stream>>>(xl, xr, row_ptr, edg, ea, meanea,
                                          We2, att2, b2, h1);
  // pooling + ffn
  pool_kernel<<<(NG + 3) / 4, 256, 0, stream>>>(h1, gstart, pooled);
  final_kernel<<<(NG + 3) / 4, 256, 0, stream>>>(pooled, Wf, bf, out);
}

// Round 14
// 873.440 us; speedup vs baseline: 1.5897x; 1.0340x over previous
//
#include <hip/hip_runtime.h>
#include <math.h>

// Problem constants (fixed by the reference)
#define NN 50000          // nodes
#define NE 800000         // edges
#define NE2 (NE + NN)     // edges + self loops = 850000
#define INC 64            // in channels
#define EDD 16            // edge dim
#define NH 4              // heads
#define CC 64             // per-head channels
#define HC 256            // H*C
#define NG 2048           // graphs
#define SLOPE 0.2f

typedef float v2f __attribute__((ext_vector_type(2)));
typedef float v4f __attribute__((ext_vector_type(4)));

#define RFL(x) __builtin_amdgcn_readfirstlane(x)

// ---------------- DPP wave-64 sum (VALU pipe, no DS traffic) ----------------
template <int CTRL, int RM>
__device__ __forceinline__ float dpp_add(float x) {
  int t = __builtin_amdgcn_update_dpp(0, __builtin_bit_cast(int, x),
                                      CTRL, RM, 0xF, false);
  return x + __builtin_bit_cast(float, t);
}
__device__ __forceinline__ float wave_sum_bcast(float x) {
  x = dpp_add<0x111, 0xF>(x);   // row_shr:1
  x = dpp_add<0x112, 0xF>(x);   // row_shr:2
  x = dpp_add<0x114, 0xF>(x);   // row_shr:4
  x = dpp_add<0x118, 0xF>(x);   // row_shr:8  -> lane15/31/47/63 = row sums
  x = dpp_add<0x142, 0xA>(x);   // row_bcast:15 -> lane31/63 = 2-row sums
  x = dpp_add<0x143, 0xC>(x);   // row_bcast:31 -> lane63 = full sum
  return __builtin_bit_cast(float,
      __builtin_amdgcn_readlane(__builtin_bit_cast(int, x), 63));
}

// ---------------- mean edge attr ----------------
__global__ void ea_sum_kernel(const float* __restrict__ ea, float* __restrict__ meansum) {
  __shared__ float part[16];
  if (threadIdx.x < 16) part[threadIdx.x] = 0.f;
  __syncthreads();
  size_t stride = (size_t)gridDim.x * blockDim.x;          // multiple of 16
  size_t i = (size_t)blockIdx.x * blockDim.x + threadIdx.x;
  int cls = (int)(i & 15);                                  // constant along loop
  float s = 0.f;
  const size_t total = (size_t)NE * EDD;
  for (; i < total; i += stride) s += ea[i];
  atomicAdd(&part[cls], s);
  __syncthreads();
  if (threadIdx.x < 16) atomicAdd(&meansum[threadIdx.x], part[threadIdx.x]);
}

// ---------------- CSR build (group edges by dst) ----------------
__global__ void count_dst_kernel(const int* __restrict__ ei, int* __restrict__ counts) {
  int e = blockIdx.x * blockDim.x + threadIdx.x;
  if (e >= NE2) return;
  int d = (e < NE) ? ei[NE + e] : (e - NE);
  atomicAdd(&counts[d], 1);
}

// 3-phase exclusive scan over n counts (n <= 256*256)
__global__ void scan_partial_kernel(const int* __restrict__ counts, int n,
                                    int* __restrict__ excl, int* __restrict__ btot) {
  int b = blockIdx.x;
  int i = b * 256 + threadIdx.x;
  int v = (i < n) ? counts[i] : 0;
  int lane = threadIdx.x & 63;
  int incl = v;
#pragma unroll
  for (int off = 1; off < 64; off <<= 1) {
    int t = __shfl_up(incl, off, 64);
    if (lane >= off) incl += t;
  }
  __shared__ int wtot[4];
  int w = threadIdx.x >> 6;
  if (lane == 63) wtot[w] = incl;
  __syncthreads();
  int woff = 0;
#pragma unroll
  for (int k = 0; k < 4; ++k) woff += (k < w) ? wtot[k] : 0;
  incl += woff;
  if (i < n) excl[i] = incl - v;
  if (threadIdx.x == 255) btot[b] = incl;
}

// scan of block totals + (fused) meanea = meansum/NE
__global__ void scan_btot_kernel(int* __restrict__ btot, int nb, int* __restrict__ totp,
                                 const float* __restrict__ meansum,
                                 float* __restrict__ meanea) {
  __shared__ int buf[256];
  int v = (threadIdx.x < nb) ? btot[threadIdx.x] : 0;
  buf[threadIdx.x] = v;
  __syncthreads();
  for (int off = 1; off < 256; off <<= 1) {
    int t = (threadIdx.x >= off) ? buf[threadIdx.x - off] : 0;
    __syncthreads();
    buf[threadIdx.x] += t;
    __syncthreads();
  }
  if (threadIdx.x < nb) btot[threadIdx.x] = buf[threadIdx.x] - v;  // exclusive
  if (threadIdx.x == 0) *totp = buf[nb - 1];                       // grand total
  if (threadIdx.x < 16) meanea[threadIdx.x] = meansum[threadIdx.x] * (1.0f / NE);
}

// scan-add + (fused) graph bounds from sorted batch
__global__ void scan_add_kernel(int* __restrict__ excl, int n, const int* __restrict__ btot,
                                const int* __restrict__ batch, int* __restrict__ gstart) {
  int i = blockIdx.x * 256 + threadIdx.x;
  if (i < n) excl[i] += btot[blockIdx.x];
  if (i < NN) {
    int b = batch[i];
    int prev = (i == 0) ? -1 : batch[i - 1];
    for (int g = prev + 1; g <= b; ++g) gstart[g] = i;
    if (i == NN - 1)
      for (int g = b + 1; g <= NG; ++g) gstart[g] = NN;
  }
}

__global__ void fill_kernel(const int* __restrict__ ei, const int* __restrict__ row_ptr,
                            int* __restrict__ cursor, int2* __restrict__ edg) {
  int e = blockIdx.x * blockDim.x + threadIdx.x;
  if (e >= NE2) return;
  int d, s;
  if (e < NE) { d = ei[NE + e]; s = ei[e]; }
  else        { d = e - NE;     s = d;     }
  int pos = row_ptr[d] + atomicAdd(&cursor[d], 1);
  edg[pos] = make_int2(e, s);
}

// ---------------- f32 GEMM: [xl|xr] = X @ [Wl|Wr], fused ----------------
// BM=128, BN=128, BK=16, 256 threads, 8x8 per-thread tile.
// grid.y: 0,1 -> Wl cols 0/128 into Yl; 2,3 -> Wr cols 0/128 into Yr.
__global__ __launch_bounds__(256, 2) void gemm2_kernel(
    const float* __restrict__ X,
    const float* __restrict__ Wl, const float* __restrict__ Wr,
    float* __restrict__ Yl, float* __restrict__ Yr, int n, int K) {
  __shared__ float Xs[16][128];
  __shared__ float Ws[16][128];
  const int tid = threadIdx.x;
  const int row0 = blockIdx.x * 128;
  const int quad = blockIdx.y;                 // 0..3
  const float* W = (quad < 2) ? Wl : Wr;
  float* Y = (quad < 2) ? Yl : Yr;
  const int col0 = (quad & 1) * 128;
  const int tr = tid >> 4, tc = tid & 15;      // 16x16 thread grid
  float acc[8][8] = {};
  for (int k0 = 0; k0 < K; k0 += 16) {
    // stage X tile transposed -> Xs[k][m]; 128 rows x 16k, 8 floats/thread
    {
      int m = tid >> 1;                        // 0..127
      int kq = (tid & 1) * 8;                  // 0 or 8
      float4 v0 = make_float4(0.f, 0.f, 0.f, 0.f);
      float4 v1 = make_float4(0.f, 0.f, 0.f, 0.f);
      int r = row0 + m;
      if (r < n) {
        v0 = *(const float4*)(X + (size_t)r * K + k0 + kq);
        v1 = *(const float4*)(X + (size_t)r * K + k0 + kq + 4);
      }
      Xs[kq + 0][m] = v0.x; Xs[kq + 1][m] = v0.y;
      Xs[kq + 2][m] = v0.z; Xs[kq + 3][m] = v0.w;
      Xs[kq + 4][m] = v1.x; Xs[kq + 5][m] = v1.y;
      Xs[kq + 6][m] = v1.z; Xs[kq + 7][m] = v1.w;
    }
    // stage W tile: Ws[k][col]; 16k x 128 cols, 8 floats/thread
    {
      int kk = tid >> 4;                       // 0..15
      int nq = (tid & 15) * 8;                 // 0..120
      float4 w0 = *(const float4*)(W + (size_t)(k0 + kk) * HC + col0 + nq);
      float4 w1 = *(const float4*)(W + (size_t)(k0 + kk) * HC + col0 + nq + 4);
      *(float4*)(&Ws[kk][nq])     = w0;
      *(float4*)(&Ws[kk][nq + 4]) = w1;
    }
    __syncthreads();
#pragma unroll
    for (int k = 0; k < 16; ++k) {
      float a[8], b[8];
      *(float4*)(a)     = *(const float4*)(&Xs[k][tr * 8]);
      *(float4*)(a + 4) = *(const float4*)(&Xs[k][tr * 8 + 4]);
      *(float4*)(b)     = *(const float4*)(&Ws[k][tc * 8]);
      *(float4*)(b + 4) = *(const float4*)(&Ws[k][tc * 8 + 4]);
#pragma unroll
      for (int i = 0; i < 8; ++i)
#pragma unroll
        for (int jj = 0; jj < 8; ++jj) acc[i][jj] += a[i] * b[jj];
    }
    __syncthreads();
  }
#pragma unroll
  for (int i = 0; i < 8; ++i) {
    int r = row0 + tr * 8 + i;
    if (r < n) {
      *(float4*)(Y + (size_t)r * HC + col0 + tc * 8) =
          make_float4(acc[i][0], acc[i][1], acc[i][2], acc[i][3]);
      *(float4*)(Y + (size_t)r * HC + col0 + tc * 8 + 4) =
          make_float4(acc[i][4], acc[i][5], acc[i][6], acc[i][7]);
    }
  }
}

// ---------------- fused edge score + softmax + aggregate ----------------
// r13 structure (one wave per (node, head), lane owns one channel, DPP
// reduction, scalar ea loads, exact tails) with per-edge VALU cuts:
// leaky = max(t, 0.2t) (slope<1) and raw v_exp_f32 via builtin.
template <int B>
__device__ __forceinline__ void edge_batch(
    int j, const int2* __restrict__ edg, const float* __restrict__ xl,
    const float* __restrict__ ea, const v2f (&wreg)[8],
    float see, float xrl, float attl, unsigned c,
    float& den, float& acc) {
  int2 E[B];
#pragma unroll
  for (int k = 0; k < B; ++k) E[k] = edg[(unsigned)(j + k)];
  float X[B];
#pragma unroll
  for (int k = 0; k < B; ++k) X[k] = xl[((unsigned)E[k].y << 8) + c];
  float q[B];
#pragma unroll
  for (int k = 0; k < B; ++k) {
    float ee;
    if (E[k].x < NE) {
      const float* eap = ea + ((size_t)((unsigned)E[k].x << 4));
      v4f a0 = *(const v4f*)(eap);
      v4f a1 = *(const v4f*)(eap + 4);
      v4f a2 = *(const v4f*)(eap + 8);
      v4f a3 = *(const v4f*)(eap + 12);
      v2f s = (v2f){a0.x, a0.y} * wreg[0] + (v2f){a0.z, a0.w} * wreg[1]
            + (v2f){a1.x, a1.y} * wreg[2] + (v2f){a1.z, a1.w} * wreg[3]
            + (v2f){a2.x, a2.y} * wreg[4] + (v2f){a2.z, a2.w} * wreg[5]
            + (v2f){a3.x, a3.y} * wreg[6] + (v2f){a3.z, a3.w} * wreg[7];
      ee = s.x + s.y;
    } else {
      ee = see;
    }
    float t = X[k] + xrl + ee;
    t = fmaxf(t, SLOPE * t);                  // leaky-relu, slope < 1
    q[k] = t * attl;
  }
#pragma unroll
  for (int k = 0; k < B; ++k) q[k] = wave_sum_bcast(q[k]);
#pragma unroll
  for (int k = 0; k < B; ++k) {
    float w = __builtin_amdgcn_exp2f(q[k]);   // bare v_exp_f32
    den += w;
    acc = fmaf(w, X[k], acc);
  }
}

__global__ __launch_bounds__(256, 4) void edge_agg_kernel(
    const float* __restrict__ xl, const float* __restrict__ xr,
    const int* __restrict__ row_ptr, const int2* __restrict__ edg,
    const float* __restrict__ ea, const float* __restrict__ meanea,
    const float* __restrict__ We, const float* __restrict__ att,
    const float* __restrict__ bias, float* __restrict__ out) {
  const int lane = threadIdx.x & 63;
  const int head = threadIdx.x >> 6;          // 0..3
  const int node = blockIdx.x;
  const unsigned c = (unsigned)head * CC + (unsigned)lane;   // channel 0..255

  v2f wreg[8];
#pragma unroll
  for (int d = 0; d < 8; ++d)
    wreg[d] = (v2f){We[(unsigned)(2 * d) * HC + c], We[(unsigned)(2 * d + 1) * HC + c]};
  const float attl = att[c] * 1.44269504088896340736f;   // fold log2(e)
  const float xrl  = xr[((unsigned)node << 8) + c];
  v2f seev = {0.f, 0.f};
#pragma unroll
  for (int d = 0; d < 8; ++d)
    seev += (v2f){meanea[2 * d], meanea[2 * d + 1]} * wreg[d];
  const float see = seev.x + seev.y;

  float den = 0.f, acc = 0.f;
  const int beg = row_ptr[node];
  const int end = row_ptr[node + 1];

  int j = beg;
  for (; j + 8 <= end; j += 8)
    edge_batch<8>(j, edg, xl, ea, wreg, see, xrl, attl, c, den, acc);
  const int rem = end - j;                    // 0..7, wave-uniform
  if (rem & 4) {
    edge_batch<4>(j, edg, xl, ea, wreg, see, xrl, attl, c, den, acc);
    j += 4;
  }
  if (rem & 2) {
    edge_batch<2>(j, edg, xl, ea, wreg, see, xrl, attl, c, den, acc);
    j += 2;
  }
  if (rem & 1) {
    edge_batch<1>(j, edg, xl, ea, wreg, see, xrl, attl, c, den, acc);
  }

  float o = fmaxf(acc / (den + 1e-16f) + bias[c], 0.f);   // fused ReLU
  out[((unsigned)node << 8) + c] = o;
}

// ---------------- global mean pool: one wave per graph ----------------
__global__ void pool_kernel(const float* __restrict__ h2, const int* __restrict__ gstart,
                            float* __restrict__ pooled) {
  int lane = threadIdx.x & 63;
  int g = blockIdx.x * 4 + (threadIdx.x >> 6);
  if (g >= NG) return;
  int s = RFL(gstart[g]), e = RFL(gstart[g + 1]);
  float sx = 0.f, sy = 0.f, sz = 0.f, sw = 0.f;
  for (int i = s; i < e; ++i) {
    float4 v = *(const float4*)(h2 + (size_t)i * HC + lane * 4);
    sx += v.x; sy += v.y; sz += v.z; sw += v.w;
  }
  float inv = 1.f / fmaxf((float)(e - s), 1.f);
  *(float4*)(pooled + (size_t)g * HC + lane * 4) =
      make_float4(sx * inv, sy * inv, sz * inv, sw * inv);
}

// ---------------- final linear: out[g] = pooled_mean . Wf + bf ----------------
__global__ void final_kernel(const float* __restrict__ pooled,
                             const float* __restrict__ Wf, const float* __restrict__ bf,
                             float* __restrict__ out) {
  int lane = threadIdx.x & 63;
  int g = blockIdx.x * (blockDim.x >> 6) + (threadIdx.x >> 6);
  if (g >= NG) return;
  float4 p = *(const float4*)(pooled + (size_t)g * HC + lane * 4);
  float4 w = *(const float4*)(Wf + lane * 4);
  float s = p.x * w.x + p.y * w.y + p.z * w.z + p.w * w.w;
  s += __shfl_xor(s, 1, 64);  s += __shfl_xor(s, 2, 64);
  s += __shfl_xor(s, 4, 64);  s += __shfl_xor(s, 8, 64);
  s += __shfl_xor(s, 16, 64); s += __shfl_xor(s, 32, 64);
  if (lane == 0) out[g] = s + bf[0];
}

extern "C" void kernel_launch(void* const* d_in, const int* in_sizes, int n_in,
                              void* d_out, int out_size, void* d_ws, size_t ws_size,
                              hipStream_t stream) {
  const float* x    = (const float*)d_in[0];
  const int*   ei   = (const int*)d_in[1];   // [2,E]: src row 0, dst row 1
  const int*   batch= (const int*)d_in[2];
  const float* ea   = (const float*)d_in[3];
  const float* Wl1  = (const float*)d_in[4];
  const float* Wr1  = (const float*)d_in[5];
  const float* We1  = (const float*)d_in[6];
  const float* att1 = (const float*)d_in[7];
  const float* b1   = (const float*)d_in[8];
  const float* Wl2  = (const float*)d_in[9];
  const float* Wr2  = (const float*)d_in[10];
  const float* We2  = (const float*)d_in[11];
  const float* att2 = (const float*)d_in[12];
  const float* b2   = (const float*)d_in[13];
  const float* Wf   = (const float*)d_in[14];
  const float* bf   = (const float*)d_in[15];
  float* out = (float*)d_out;

  // workspace layout
  float* xl      = (float*)d_ws;               // N*256
  float* xr      = xl + (size_t)NN * HC;       // N*256
  float* h1      = xr + (size_t)NN * HC;       // N*256
  float* pooled  = h1 + (size_t)NN * HC;       // G*256
  float* meansum = pooled + (size_t)NG * HC;   // 16
  float* meanea  = meansum + 16;               // 16
  int* counts  = (int*)(meanea + 16);          // N
  int* row_ptr = counts + NN;                  // N+1
  int* btot    = row_ptr + NN + 1;             // 256
  int* gstart  = btot + 256;                   // G+1
  int2* edg    = (int2*)(gstart + NG + 1);     // E2 (8B aligned: offset even)

  const int NB = (NN + 255) / 256;             // 196 scan blocks

  hipMemsetAsync(counts, 0, NN * sizeof(int), stream);
  hipMemsetAsync(meansum, 0, 16 * sizeof(float), stream);

  ea_sum_kernel<<<1024, 256, 0, stream>>>(ea, meansum);

  count_dst_kernel<<<(NE2 + 255) / 256, 256, 0, stream>>>(ei, counts);
  scan_partial_kernel<<<NB, 256, 0, stream>>>(counts, NN, row_ptr, btot);
  scan_btot_kernel<<<1, 256, 0, stream>>>(btot, NB, row_ptr + NN, meansum, meanea);
  scan_add_kernel<<<NB, 256, 0, stream>>>(row_ptr, NN, btot, batch, gstart);
  hipMemsetAsync(counts, 0, NN * sizeof(int), stream);
  fill_kernel<<<(NE2 + 255) / 256, 256, 0, stream>>>(ei, row_ptr, counts, edg);

  dim3 ggrid((NN + 127) / 128, 4);
  // layer 1 (fused Wl|Wr GEMM)
  gemm2_kernel<<<ggrid, 256, 0, stream>>>(x, Wl1, Wr1, xl, xr, NN, INC);
  edge_agg_kernel<<<NN, 256, 0, stream>>>(xl, xr, row_ptr, edg, ea, meanea,
                                          We1, att1, b1, h1);
  // layer 2 (reuse xl/xr buffers)
  gemm2_kernel<<<ggrid, 256, 0, stream>>>(h1, Wl2, Wr2, xl, xr, NN, HC);
  edge_agg_kernel<<<NN, 256, 0, stream>>>(xl, xr, row_ptr, edg, ea, meanea,
                                          We2, att2, b2, h1);
  // pooling + ffn
  pool_kernel<<<(NG + 3) / 4, 256, 0, stream>>>(h1, gstart, pooled);
  final_kernel<<<(NG + 3) / 4, 256, 0, stream>>>(pooled, Wf, bf, out);
}

// Round 15
// 815.849 us; speedup vs baseline: 1.7019x; 1.0706x over previous
//
#include <hip/hip_runtime.h>
#include <math.h>

// Problem constants (fixed by the reference)
#define NN 50000          // nodes
#define NE 800000         // edges
#define NE2 (NE + NN)     // edges + self loops = 850000
#define INC 64            // in channels
#define EDD 16            // edge dim
#define NH 4              // heads
#define CC 64             // per-head channels
#define HC 256            // H*C
#define NG 2048           // graphs
#define SLOPE 0.2f

typedef float v2f __attribute__((ext_vector_type(2)));
typedef float v4f __attribute__((ext_vector_type(4)));
typedef __bf16 bf16x8 __attribute__((ext_vector_type(8)));
typedef float f32x4 __attribute__((ext_vector_type(4)));
typedef unsigned short ushort8v __attribute__((ext_vector_type(8)));

#define RFL(x) __builtin_amdgcn_readfirstlane(x)

// f32 -> bf16 (rne) and back
__device__ __forceinline__ unsigned short f2bf(float f) {
  unsigned u = __builtin_bit_cast(unsigned, f);
  u += 0x7FFF + ((u >> 16) & 1);
  return (unsigned short)(u >> 16);
}
__device__ __forceinline__ float bf2f(unsigned short h) {
  return __builtin_bit_cast(float, ((unsigned)h) << 16);
}

// ---------------- DPP wave-64 sum (VALU pipe, no DS traffic) ----------------
template <int CTRL, int RM>
__device__ __forceinline__ float dpp_add(float x) {
  int t = __builtin_amdgcn_update_dpp(0, __builtin_bit_cast(int, x),
                                      CTRL, RM, 0xF, false);
  return x + __builtin_bit_cast(float, t);
}
__device__ __forceinline__ float wave_sum_bcast(float x) {
  x = dpp_add<0x111, 0xF>(x);   // row_shr:1
  x = dpp_add<0x112, 0xF>(x);   // row_shr:2
  x = dpp_add<0x114, 0xF>(x);   // row_shr:4
  x = dpp_add<0x118, 0xF>(x);   // row_shr:8
  x = dpp_add<0x142, 0xA>(x);   // row_bcast:15
  x = dpp_add<0x143, 0xC>(x);   // row_bcast:31 -> lane63 = full sum
  return __builtin_bit_cast(float,
      __builtin_amdgcn_readlane(__builtin_bit_cast(int, x), 63));
}

// ---------------- mean edge attr ----------------
__global__ void ea_sum_kernel(const float* __restrict__ ea, float* __restrict__ meansum) {
  __shared__ float part[16];
  if (threadIdx.x < 16) part[threadIdx.x] = 0.f;
  __syncthreads();
  size_t stride = (size_t)gridDim.x * blockDim.x;
  size_t i = (size_t)blockIdx.x * blockDim.x + threadIdx.x;
  int cls = (int)(i & 15);
  float s = 0.f;
  const size_t total = (size_t)NE * EDD;
  for (; i < total; i += stride) s += ea[i];
  atomicAdd(&part[cls], s);
  __syncthreads();
  if (threadIdx.x < 16) atomicAdd(&meansum[threadIdx.x], part[threadIdx.x]);
}

// ---------------- CSR build ----------------
__global__ void count_dst_kernel(const int* __restrict__ ei, int* __restrict__ counts) {
  int e = blockIdx.x * blockDim.x + threadIdx.x;
  if (e >= NE2) return;
  int d = (e < NE) ? ei[NE + e] : (e - NE);
  atomicAdd(&counts[d], 1);
}

__global__ void scan_partial_kernel(const int* __restrict__ counts, int n,
                                    int* __restrict__ excl, int* __restrict__ btot) {
  int b = blockIdx.x;
  int i = b * 256 + threadIdx.x;
  int v = (i < n) ? counts[i] : 0;
  int lane = threadIdx.x & 63;
  int incl = v;
#pragma unroll
  for (int off = 1; off < 64; off <<= 1) {
    int t = __shfl_up(incl, off, 64);
    if (lane >= off) incl += t;
  }
  __shared__ int wtot[4];
  int w = threadIdx.x >> 6;
  if (lane == 63) wtot[w] = incl;
  __syncthreads();
  int woff = 0;
#pragma unroll
  for (int k = 0; k < 4; ++k) woff += (k < w) ? wtot[k] : 0;
  incl += woff;
  if (i < n) excl[i] = incl - v;
  if (threadIdx.x == 255) btot[b] = incl;
}

__global__ void scan_btot_kernel(int* __restrict__ btot, int nb, int* __restrict__ totp,
                                 const float* __restrict__ meansum,
                                 float* __restrict__ meanea) {
  __shared__ int buf[256];
  int v = (threadIdx.x < nb) ? btot[threadIdx.x] : 0;
  buf[threadIdx.x] = v;
  __syncthreads();
  for (int off = 1; off < 256; off <<= 1) {
    int t = (threadIdx.x >= off) ? buf[threadIdx.x - off] : 0;
    __syncthreads();
    buf[threadIdx.x] += t;
    __syncthreads();
  }
  if (threadIdx.x < nb) btot[threadIdx.x] = buf[threadIdx.x] - v;
  if (threadIdx.x == 0) *totp = buf[nb - 1];
  if (threadIdx.x < 16) meanea[threadIdx.x] = meansum[threadIdx.x] * (1.0f / NE);
}

__global__ void scan_add_kernel(int* __restrict__ excl, int n, const int* __restrict__ btot,
                                const int* __restrict__ batch, int* __restrict__ gstart) {
  int i = blockIdx.x * 256 + threadIdx.x;
  if (i < n) excl[i] += btot[blockIdx.x];
  if (i < NN) {
    int b = batch[i];
    int prev = (i == 0) ? -1 : batch[i - 1];
    for (int g = prev + 1; g <= b; ++g) gstart[g] = i;
    if (i == NN - 1)
      for (int g = b + 1; g <= NG; ++g) gstart[g] = NN;
  }
}

__global__ void fill_kernel(const int* __restrict__ ei, const int* __restrict__ row_ptr,
                            int* __restrict__ cursor, int2* __restrict__ edg) {
  int e = blockIdx.x * blockDim.x + threadIdx.x;
  if (e >= NE2) return;
  int d, s;
  if (e < NE) { d = ei[NE + e]; s = ei[e]; }
  else        { d = e - NE;     s = d;     }
  int pos = row_ptr[d] + atomicAdd(&cursor[d], 1);
  edg[pos] = make_int2(e, s);
}

// ---------------- bf16 split helpers ----------------
// elementwise: src f32 -> hi/lo bf16 (vectorized by 4)
__global__ void split4_kernel(const float* __restrict__ src, unsigned short* __restrict__ hi,
                              unsigned short* __restrict__ lo, int total4) {
  int i = blockIdx.x * blockDim.x + threadIdx.x;
  if (i >= total4) return;
  float4 v = ((const float4*)src)[i];
  ushort4 h, l;
  h.x = f2bf(v.x); l.x = f2bf(v.x - bf2f(h.x));
  h.y = f2bf(v.y); l.y = f2bf(v.y - bf2f(h.y));
  h.z = f2bf(v.z); l.z = f2bf(v.z - bf2f(h.z));
  h.w = f2bf(v.w); l.w = f2bf(v.w - bf2f(h.w));
  ((ushort4*)hi)[i] = h;
  ((ushort4*)lo)[i] = l;
}

// W [K][256] f32 -> transposed Wt_hi/lo [256][K] bf16
__global__ void split_wt_kernel(const float* __restrict__ W, int K,
                                unsigned short* __restrict__ hi,
                                unsigned short* __restrict__ lo) {
  int idx = blockIdx.x * blockDim.x + threadIdx.x;
  if (idx >= K * HC) return;
  int k = idx >> 8, c = idx & 255;
  float v = W[idx];
  unsigned short h = f2bf(v);
  hi[c * K + k] = h;
  lo[c * K + k] = f2bf(v - bf2f(h));
}

// ---------------- MFMA bf16-split GEMM ----------------
// Y[n,256] = X @ W via Xhi*Whi + Xhi*Wlo + Xlo*Whi (error ~2^-17 rel).
// Block: 128x128 tile, 4 waves (2x2 of 64x64), 16x16x32 MFMA.
// quad = blockIdx.y: 0,1 -> (Wl, Yl) cols 0/128; 2,3 -> (Wr, Yr).
// Wt arrays are [256][K] (transposed) so B-fragments read contiguous.
__global__ __launch_bounds__(256, 2) void gemm_mfma_kernel(
    const unsigned short* __restrict__ Ahi, const unsigned short* __restrict__ Alo,
    const unsigned short* __restrict__ Wlhi, const unsigned short* __restrict__ Wllo,
    const unsigned short* __restrict__ Wrhi, const unsigned short* __restrict__ Wrlo,
    float* __restrict__ Yl, float* __restrict__ Yr, int n, int K) {
  __shared__ unsigned short As[128][40];   // +8 pad: conflict-free b128 reads
  __shared__ unsigned short Bs[128][40];
  const int t = threadIdx.x;
  const int row0 = blockIdx.x * 128;
  const int quad = blockIdx.y;
  const unsigned short* Bhi = (quad < 2) ? Wlhi : Wrhi;
  const unsigned short* Blo = (quad < 2) ? Wllo : Wrlo;
  float* Y = (quad < 2) ? Yl : Yr;
  const int colbase = (quad & 1) * 128;
  const int l = t & 63, w = t >> 6;
  const int mw = (w >> 1) * 64, nw = (w & 1) * 64;
  const int lr = l & 15, lk = (l >> 4) * 8;
  const int srow = t >> 1, scb = (t & 1) << 4;   // staging: row, col-base (16 bf16)

  f32x4 acc[4][4] = {};
  for (int seg = 0; seg < 3; ++seg) {
    const unsigned short* Aseg = (seg == 2) ? Alo : Ahi;
    const unsigned short* Bseg = (seg == 1) ? Blo : Bhi;
    for (int k0 = 0; k0 < K; k0 += 32) {
      // stage A tile [128][32]
      {
        uint4 v0 = {0, 0, 0, 0}, v1 = {0, 0, 0, 0};
        int r = row0 + srow;
        if (r < n) {
          const uint4* p = (const uint4*)(Aseg + (size_t)r * K + k0 + scb);
          v0 = p[0]; v1 = p[1];
        }
        *(uint4*)(&As[srow][scb])     = v0;
        *(uint4*)(&As[srow][scb + 8]) = v1;
      }
      // stage B tile [128 n][32 k] from Wt[256][K]
      {
        const uint4* p = (const uint4*)(Bseg + (size_t)(colbase + srow) * K + k0 + scb);
        *(uint4*)(&Bs[srow][scb])     = p[0];
        *(uint4*)(&Bs[srow][scb + 8]) = p[1];
      }
      __syncthreads();
      bf16x8 a[4], b[4];
#pragma unroll
      for (int i = 0; i < 4; ++i)
        a[i] = __builtin_bit_cast(bf16x8, *(const ushort8v*)(&As[mw + i * 16 + lr][lk]));
#pragma unroll
      for (int j = 0; j < 4; ++j)
        b[j] = __builtin_bit_cast(bf16x8, *(const ushort8v*)(&Bs[nw + j * 16 + lr][lk]));
#pragma unroll
      for (int i = 0; i < 4; ++i)
#pragma unroll
        for (int j = 0; j < 4; ++j)
          acc[i][j] = __builtin_amdgcn_mfma_f32_16x16x32_bf16(a[i], b[j], acc[i][j], 0, 0, 0);
      __syncthreads();
    }
  }
  // epilogue: D frag layout col=lane&15, row=(lane>>4)*4+reg [m89-verified]
#pragma unroll
  for (int i = 0; i < 4; ++i)
#pragma unroll
    for (int j = 0; j < 4; ++j) {
      int colg = colbase + nw + j * 16 + lr;
#pragma unroll
      for (int r = 0; r < 4; ++r) {
        int row = row0 + mw + i * 16 + (l >> 4) * 4 + r;
        if (row < n) Y[(size_t)row * HC + colg] = acc[i][j][r];
      }
    }
}

// ---------------- f32 GEMM (fallback when ws too small) ----------------
__global__ __launch_bounds__(256, 2) void gemm2_kernel(
    const float* __restrict__ X,
    const float* __restrict__ Wl, const float* __restrict__ Wr,
    float* __restrict__ Yl, float* __restrict__ Yr, int n, int K) {
  __shared__ float Xs[16][128];
  __shared__ float Ws[16][128];
  const int tid = threadIdx.x;
  const int row0 = blockIdx.x * 128;
  const int quad = blockIdx.y;
  const float* W = (quad < 2) ? Wl : Wr;
  float* Y = (quad < 2) ? Yl : Yr;
  const int col0 = (quad & 1) * 128;
  const int tr = tid >> 4, tc = tid & 15;
  float acc[8][8] = {};
  for (int k0 = 0; k0 < K; k0 += 16) {
    {
      int m = tid >> 1;
      int kq = (tid & 1) * 8;
      float4 v0 = make_float4(0.f, 0.f, 0.f, 0.f);
      float4 v1 = make_float4(0.f, 0.f, 0.f, 0.f);
      int r = row0 + m;
      if (r < n) {
        v0 = *(const float4*)(X + (size_t)r * K + k0 + kq);
        v1 = *(const float4*)(X + (size_t)r * K + k0 + kq + 4);
      }
      Xs[kq + 0][m] = v0.x; Xs[kq + 1][m] = v0.y;
      Xs[kq + 2][m] = v0.z; Xs[kq + 3][m] = v0.w;
      Xs[kq + 4][m] = v1.x; Xs[kq + 5][m] = v1.y;
      Xs[kq + 6][m] = v1.z; Xs[kq + 7][m] = v1.w;
    }
    {
      int kk = tid >> 4;
      int nq = (tid & 15) * 8;
      float4 w0 = *(const float4*)(W + (size_t)(k0 + kk) * HC + col0 + nq);
      float4 w1 = *(const float4*)(W + (size_t)(k0 + kk) * HC + col0 + nq + 4);
      *(float4*)(&Ws[kk][nq])     = w0;
      *(float4*)(&Ws[kk][nq + 4]) = w1;
    }
    __syncthreads();
#pragma unroll
    for (int k = 0; k < 16; ++k) {
      float a[8], b[8];
      *(float4*)(a)     = *(const float4*)(&Xs[k][tr * 8]);
      *(float4*)(a + 4) = *(const float4*)(&Xs[k][tr * 8 + 4]);
      *(float4*)(b)     = *(const float4*)(&Ws[k][tc * 8]);
      *(float4*)(b + 4) = *(const float4*)(&Ws[k][tc * 8 + 4]);
#pragma unroll
      for (int i = 0; i < 8; ++i)
#pragma unroll
        for (int jj = 0; jj < 8; ++jj) acc[i][jj] += a[i] * b[jj];
    }
    __syncthreads();
  }
#pragma unroll
  for (int i = 0; i < 8; ++i) {
    int r = row0 + tr * 8 + i;
    if (r < n) {
      *(float4*)(Y + (size_t)r * HC + col0 + tc * 8) =
          make_float4(acc[i][0], acc[i][1], acc[i][2], acc[i][3]);
      *(float4*)(Y + (size_t)r * HC + col0 + tc * 8 + 4) =
          make_float4(acc[i][4], acc[i][5], acc[i][6], acc[i][7]);
    }
  }
}

// ---------------- fused edge score + softmax + aggregate (r14) ----------------
template <int B>
__device__ __forceinline__ void edge_batch(
    int j, const int2* __restrict__ edg, const float* __restrict__ xl,
    const float* __restrict__ ea, const v2f (&wreg)[8],
    float see, float xrl, float attl, unsigned c,
    float& den, float& acc) {
  int2 E[B];
#pragma unroll
  for (int k = 0; k < B; ++k) E[k] = edg[(unsigned)(j + k)];
  float X[B];
#pragma unroll
  for (int k = 0; k < B; ++k) X[k] = xl[((unsigned)E[k].y << 8) + c];
  float q[B];
#pragma unroll
  for (int k = 0; k < B; ++k) {
    float ee;
    if (E[k].x < NE) {
      const float* eap = ea + ((size_t)((unsigned)E[k].x << 4));
      v4f a0 = *(const v4f*)(eap);
      v4f a1 = *(const v4f*)(eap + 4);
      v4f a2 = *(const v4f*)(eap + 8);
      v4f a3 = *(const v4f*)(eap + 12);
      v2f s = (v2f){a0.x, a0.y} * wreg[0] + (v2f){a0.z, a0.w} * wreg[1]
            + (v2f){a1.x, a1.y} * wreg[2] + (v2f){a1.z, a1.w} * wreg[3]
            + (v2f){a2.x, a2.y} * wreg[4] + (v2f){a2.z, a2.w} * wreg[5]
            + (v2f){a3.x, a3.y} * wreg[6] + (v2f){a3.z, a3.w} * wreg[7];
      ee = s.x + s.y;
    } else {
      ee = see;
    }
    float t = X[k] + xrl + ee;
    t = fmaxf(t, SLOPE * t);
    q[k] = t * attl;
  }
#pragma unroll
  for (int k = 0; k < B; ++k) q[k] = wave_sum_bcast(q[k]);
#pragma unroll
  for (int k = 0; k < B; ++k) {
    float w = __builtin_amdgcn_exp2f(q[k]);
    den += w;
    acc = fmaf(w, X[k], acc);
  }
}

__global__ __launch_bounds__(256, 4) void edge_agg_kernel(
    const float* __restrict__ xl, const float* __restrict__ xr,
    const int* __restrict__ row_ptr, const int2* __restrict__ edg,
    const float* __restrict__ ea, const float* __restrict__ meanea,
    const float* __restrict__ We, const float* __restrict__ att,
    const float* __restrict__ bias, float* __restrict__ out,
    unsigned short* __restrict__ outhi, unsigned short* __restrict__ outlo) {
  const int lane = threadIdx.x & 63;
  const int head = threadIdx.x >> 6;
  const int node = blockIdx.x;
  const unsigned c = (unsigned)head * CC + (unsigned)lane;

  v2f wreg[8];
#pragma unroll
  for (int d = 0; d < 8; ++d)
    wreg[d] = (v2f){We[(unsigned)(2 * d) * HC + c], We[(unsigned)(2 * d + 1) * HC + c]};
  const float attl = att[c] * 1.44269504088896340736f;
  const float xrl  = xr[((unsigned)node << 8) + c];
  v2f seev = {0.f, 0.f};
#pragma unroll
  for (int d = 0; d < 8; ++d)
    seev += (v2f){meanea[2 * d], meanea[2 * d + 1]} * wreg[d];
  const float see = seev.x + seev.y;

  float den = 0.f, acc = 0.f;
  const int beg = row_ptr[node];
  const int end = row_ptr[node + 1];

  int j = beg;
  for (; j + 8 <= end; j += 8)
    edge_batch<8>(j, edg, xl, ea, wreg, see, xrl, attl, c, den, acc);
  const int rem = end - j;
  if (rem & 4) {
    edge_batch<4>(j, edg, xl, ea, wreg, see, xrl, attl, c, den, acc);
    j += 4;
  }
  if (rem & 2) {
    edge_batch<2>(j, edg, xl, ea, wreg, see, xrl, attl, c, den, acc);
    j += 2;
  }
  if (rem & 1) {
    edge_batch<1>(j, edg, xl, ea, wreg, see, xrl, attl, c, den, acc);
  }

  float o = fmaxf(acc / (den + 1e-16f) + bias[c], 0.f);
  unsigned idx = ((unsigned)node << 8) + c;
  if (outhi) {           // write bf16 split (feeds MFMA GEMM of next layer)
    unsigned short h = f2bf(o);
    outhi[idx] = h;
    outlo[idx] = f2bf(o - bf2f(h));
  } else {
    out[idx] = o;
  }
}

// ---------------- global mean pool: one wave per graph ----------------
__global__ void pool_kernel(const float* __restrict__ h2, const int* __restrict__ gstart,
                            float* __restrict__ pooled) {
  int lane = threadIdx.x & 63;
  int g = blockIdx.x * 4 + (threadIdx.x >> 6);
  if (g >= NG) return;
  int s = RFL(gstart[g]), e = RFL(gstart[g + 1]);
  float sx = 0.f, sy = 0.f, sz = 0.f, sw = 0.f;
  for (int i = s; i < e; ++i) {
    float4 v = *(const float4*)(h2 + (size_t)i * HC + lane * 4);
    sx += v.x; sy += v.y; sz += v.z; sw += v.w;
  }
  float inv = 1.f / fmaxf((float)(e - s), 1.f);
  *(float4*)(pooled + (size_t)g * HC + lane * 4) =
      make_float4(sx * inv, sy * inv, sz * inv, sw * inv);
}

// ---------------- final linear ----------------
__global__ void final_kernel(const float* __restrict__ pooled,
                             const float* __restrict__ Wf, const float* __restrict__ bf,
                             float* __restrict__ out) {
  int lane = threadIdx.x & 63;
  int g = blockIdx.x * (blockDim.x >> 6) + (threadIdx.x >> 6);
  if (g >= NG) return;
  float4 p = *(const float4*)(pooled + (size_t)g * HC + lane * 4);
  float4 w = *(const float4*)(Wf + lane * 4);
  float s = p.x * w.x + p.y * w.y + p.z * w.z + p.w * w.w;
  s += __shfl_xor(s, 1, 64);  s += __shfl_xor(s, 2, 64);
  s += __shfl_xor(s, 4, 64);  s += __shfl_xor(s, 8, 64);
  s += __shfl_xor(s, 16, 64); s += __shfl_xor(s, 32, 64);
  if (lane == 0) out[g] = s + bf[0];
}

extern "C" void kernel_launch(void* const* d_in, const int* in_sizes, int n_in,
                              void* d_out, int out_size, void* d_ws, size_t ws_size,
                              hipStream_t stream) {
  const float* x    = (const float*)d_in[0];
  const int*   ei   = (const int*)d_in[1];
  const int*   batch= (const int*)d_in[2];
  const float* ea   = (const float*)d_in[3];
  const float* Wl1  = (const float*)d_in[4];
  const float* Wr1  = (const float*)d_in[5];
  const float* We1  = (const float*)d_in[6];
  const float* att1 = (const float*)d_in[7];
  const float* b1   = (const float*)d_in[8];
  const float* Wl2  = (const float*)d_in[9];
  const float* Wr2  = (const float*)d_in[10];
  const float* We2  = (const float*)d_in[11];
  const float* att2 = (const float*)d_in[12];
  const float* b2   = (const float*)d_in[13];
  const float* Wf   = (const float*)d_in[14];
  const float* bf   = (const float*)d_in[15];
  float* out = (float*)d_out;

  // ---- workspace layout (f32, then ints, then bf16/ushort) ----
  float* xl      = (float*)d_ws;               // N*256
  float* xr      = xl + (size_t)NN * HC;       // N*256
  float* h1      = xr + (size_t)NN * HC;       // N*256
  float* pooled  = h1 + (size_t)NN * HC;       // G*256
  float* meansum = pooled + (size_t)NG * HC;   // 16
  float* meanea  = meansum + 16;               // 16
  int* counts  = (int*)(meanea + 16);          // N
  int* row_ptr = counts + NN;                  // N+1
  int* btot    = row_ptr + NN + 1;             // 256
  int* gstart  = btot + 256;                   // G+1 (+1 pad for 8B align)
  int2* edg    = (int2*)(gstart + NG + 2);     // E2
  unsigned short* Xhi  = (unsigned short*)(edg + NE2);  // N*64
  unsigned short* Xlo  = Xhi + (size_t)NN * INC;        // N*64
  unsigned short* Hhi  = Xlo + (size_t)NN * INC;        // N*256
  unsigned short* Hlo  = Hhi + (size_t)NN * HC;         // N*256
  unsigned short* Wlh1 = Hlo + (size_t)NN * HC;         // 256*64
  unsigned short* Wll1 = Wlh1 + HC * INC;
  unsigned short* Wrh1 = Wll1 + HC * INC;
  unsigned short* Wrl1 = Wrh1 + HC * INC;
  unsigned short* Wlh2 = Wrl1 + HC * INC;               // 256*256
  unsigned short* Wll2 = Wlh2 + HC * HC;
  unsigned short* Wrh2 = Wll2 + HC * HC;
  unsigned short* Wrl2 = Wrh2 + HC * HC;
  size_t need = (size_t)((char*)(Wrl2 + HC * HC) - (char*)d_ws);
  const bool use_mfma = (ws_size >= need);

  const int NB = (NN + 255) / 256;

  hipMemsetAsync(counts, 0, NN * sizeof(int), stream);
  hipMemsetAsync(meansum, 0, 16 * sizeof(float), stream);

  ea_sum_kernel<<<1024, 256, 0, stream>>>(ea, meansum);

  count_dst_kernel<<<(NE2 + 255) / 256, 256, 0, stream>>>(ei, counts);
  scan_partial_kernel<<<NB, 256, 0, stream>>>(counts, NN, row_ptr, btot);
  scan_btot_kernel<<<1, 256, 0, stream>>>(btot, NB, row_ptr + NN, meansum, meanea);
  scan_add_kernel<<<NB, 256, 0, stream>>>(row_ptr, NN, btot, batch, gstart);
  hipMemsetAsync(counts, 0, NN * sizeof(int), stream);
  fill_kernel<<<(NE2 + 255) / 256, 256, 0, stream>>>(ei, row_ptr, counts, edg);

  if (use_mfma) {
    // split inputs & weights to bf16 hi/lo
    split4_kernel<<<(NN * INC / 4 + 255) / 256, 256, 0, stream>>>(x, Xhi, Xlo, NN * INC / 4);
    split_wt_kernel<<<(INC * HC + 255) / 256, 256, 0, stream>>>(Wl1, INC, Wlh1, Wll1);
    split_wt_kernel<<<(INC * HC + 255) / 256, 256, 0, stream>>>(Wr1, INC, Wrh1, Wrl1);
    split_wt_kernel<<<(HC * HC + 255) / 256, 256, 0, stream>>>(Wl2, HC, Wlh2, Wll2);
    split_wt_kernel<<<(HC * HC + 255) / 256, 256, 0, stream>>>(Wr2, HC, Wrh2, Wrl2);

    dim3 mgrid((NN + 127) / 128, 4);
    // layer 1: [xl|xr] = x @ [Wl1|Wr1] via 3-product bf16 MFMA
    gemm_mfma_kernel<<<mgrid, 256, 0, stream>>>(Xhi, Xlo, Wlh1, Wll1, Wrh1, Wrl1,
                                                xl, xr, NN, INC);
    // edge_agg L1 writes bf16 split directly (feeds L2 GEMM)
    edge_agg_kernel<<<NN, 256, 0, stream>>>(xl, xr, row_ptr, edg, ea, meanea,
                                            We1, att1, b1, nullptr, Hhi, Hlo);
    // layer 2
    gemm_mfma_kernel<<<mgrid, 256, 0, stream>>>(Hhi, Hlo, Wlh2, Wll2, Wrh2, Wrl2,
                                                xl, xr, NN, HC);
    edge_agg_kernel<<<NN, 256, 0, stream>>>(xl, xr, row_ptr, edg, ea, meanea,
                                            We2, att2, b2, h1, nullptr, nullptr);
  } else {
    // fallback: proven f32 path (r14)
    dim3 ggrid((NN + 127) / 128, 4);
    gemm2_kernel<<<ggrid, 256, 0, stream>>>(x, Wl1, Wr1, xl, xr, NN, INC);
    edge_agg_kernel<<<NN, 256, 0, stream>>>(xl, xr, row_ptr, edg, ea, meanea,
                                            We1, att1, b1, h1, nullptr, nullptr);
    gemm2_kernel<<<ggrid, 256, 0, stream>>>(h1, Wl2, Wr2, xl, xr, NN, HC);
    edge_agg_kernel<<<NN, 256, 0, stream>>>(xl, xr, row_ptr, edg, ea, meanea,
                                            We2, att2, b2, h1, nullptr, nullptr);
  }

  // pooling + ffn
  pool_kernel<<<(NG + 3) / 4, 256, 0, stream>>>(h1, gstart, pooled);
  final_kernel<<<(NG + 3) / 4, 256, 0, stream>>>(pooled, Wf, bf, out);
}

// Round 16
// 799.300 us; speedup vs baseline: 1.7371x; 1.0207x over previous
//
#include <hip/hip_runtime.h>
#include <math.h>

// Problem constants (fixed by the reference)
#define NN 50000          // nodes
#define NE 800000         // edges
#define NE2 (NE + NN)     // edges + self loops = 850000
#define INC 64            // in channels
#define EDD 16            // edge dim
#define NH 4              // heads
#define CC 64             // per-head channels
#define HC 256            // H*C
#define NG 2048           // graphs
#define SLOPE 0.2f

typedef float v2f __attribute__((ext_vector_type(2)));
typedef float v4f __attribute__((ext_vector_type(4)));
typedef __bf16 bf16x8 __attribute__((ext_vector_type(8)));
typedef float f32x4 __attribute__((ext_vector_type(4)));
typedef unsigned short ushort8v __attribute__((ext_vector_type(8)));

#define RFL(x) __builtin_amdgcn_readfirstlane(x)

// f32 -> bf16 (rne) and back
__device__ __forceinline__ unsigned short f2bf(float f) {
  unsigned u = __builtin_bit_cast(unsigned, f);
  u += 0x7FFF + ((u >> 16) & 1);
  return (unsigned short)(u >> 16);
}
__device__ __forceinline__ float bf2f(unsigned short h) {
  return __builtin_bit_cast(float, ((unsigned)h) << 16);
}

// ---------------- DPP wave-64 sum (VALU pipe, no DS traffic) ----------------
template <int CTRL, int RM>
__device__ __forceinline__ float dpp_add(float x) {
  int t = __builtin_amdgcn_update_dpp(0, __builtin_bit_cast(int, x),
                                      CTRL, RM, 0xF, false);
  return x + __builtin_bit_cast(float, t);
}
__device__ __forceinline__ float wave_sum_bcast(float x) {
  x = dpp_add<0x111, 0xF>(x);   // row_shr:1
  x = dpp_add<0x112, 0xF>(x);   // row_shr:2
  x = dpp_add<0x114, 0xF>(x);   // row_shr:4
  x = dpp_add<0x118, 0xF>(x);   // row_shr:8
  x = dpp_add<0x142, 0xA>(x);   // row_bcast:15
  x = dpp_add<0x143, 0xC>(x);   // row_bcast:31 -> lane63 = full sum
  return __builtin_bit_cast(float,
      __builtin_amdgcn_readlane(__builtin_bit_cast(int, x), 63));
}

// ---------------- mean edge attr ----------------
__global__ void ea_sum_kernel(const float* __restrict__ ea, float* __restrict__ meansum) {
  __shared__ float part[16];
  if (threadIdx.x < 16) part[threadIdx.x] = 0.f;
  __syncthreads();
  size_t stride = (size_t)gridDim.x * blockDim.x;
  size_t i = (size_t)blockIdx.x * blockDim.x + threadIdx.x;
  int cls = (int)(i & 15);
  float s = 0.f;
  const size_t total = (size_t)NE * EDD;
  for (; i < total; i += stride) s += ea[i];
  atomicAdd(&part[cls], s);
  __syncthreads();
  if (threadIdx.x < 16) atomicAdd(&meansum[threadIdx.x], part[threadIdx.x]);
}

// ---------------- CSR build ----------------
__global__ void count_dst_kernel(const int* __restrict__ ei, int* __restrict__ counts) {
  int e = blockIdx.x * blockDim.x + threadIdx.x;
  if (e >= NE2) return;
  int d = (e < NE) ? ei[NE + e] : (e - NE);
  atomicAdd(&counts[d], 1);
}

__global__ void scan_partial_kernel(const int* __restrict__ counts, int n,
                                    int* __restrict__ excl, int* __restrict__ btot) {
  int b = blockIdx.x;
  int i = b * 256 + threadIdx.x;
  int v = (i < n) ? counts[i] : 0;
  int lane = threadIdx.x & 63;
  int incl = v;
#pragma unroll
  for (int off = 1; off < 64; off <<= 1) {
    int t = __shfl_up(incl, off, 64);
    if (lane >= off) incl += t;
  }
  __shared__ int wtot[4];
  int w = threadIdx.x >> 6;
  if (lane == 63) wtot[w] = incl;
  __syncthreads();
  int woff = 0;
#pragma unroll
  for (int k = 0; k < 4; ++k) woff += (k < w) ? wtot[k] : 0;
  incl += woff;
  if (i < n) excl[i] = incl - v;
  if (threadIdx.x == 255) btot[b] = incl;
}

__global__ void scan_btot_kernel(int* __restrict__ btot, int nb, int* __restrict__ totp,
                                 const float* __restrict__ meansum,
                                 float* __restrict__ meanea) {
  __shared__ int buf[256];
  int v = (threadIdx.x < nb) ? btot[threadIdx.x] : 0;
  buf[threadIdx.x] = v;
  __syncthreads();
  for (int off = 1; off < 256; off <<= 1) {
    int t = (threadIdx.x >= off) ? buf[threadIdx.x - off] : 0;
    __syncthreads();
    buf[threadIdx.x] += t;
    __syncthreads();
  }
  if (threadIdx.x < nb) btot[threadIdx.x] = buf[threadIdx.x] - v;
  if (threadIdx.x == 0) *totp = buf[nb - 1];
  if (threadIdx.x < 16) meanea[threadIdx.x] = meansum[threadIdx.x] * (1.0f / NE);
}

__global__ void scan_add_kernel(int* __restrict__ excl, int n, const int* __restrict__ btot,
                                const int* __restrict__ batch, int* __restrict__ gstart) {
  int i = blockIdx.x * 256 + threadIdx.x;
  if (i < n) excl[i] += btot[blockIdx.x];
  if (i < NN) {
    int b = batch[i];
    int prev = (i == 0) ? -1 : batch[i - 1];
    for (int g = prev + 1; g <= b; ++g) gstart[g] = i;
    if (i == NN - 1)
      for (int g = b + 1; g <= NG; ++g) gstart[g] = NN;
  }
}

__global__ void fill_kernel(const int* __restrict__ ei, const int* __restrict__ row_ptr,
                            int* __restrict__ cursor, int2* __restrict__ edg) {
  int e = blockIdx.x * blockDim.x + threadIdx.x;
  if (e >= NE2) return;
  int d, s;
  if (e < NE) { d = ei[NE + e]; s = ei[e]; }
  else        { d = e - NE;     s = d;     }
  int pos = row_ptr[d] + atomicAdd(&cursor[d], 1);
  edg[pos] = make_int2(e, s);
}

// ---------------- bf16 split helpers ----------------
__global__ void split4_kernel(const float* __restrict__ src, unsigned short* __restrict__ hi,
                              unsigned short* __restrict__ lo, int total4) {
  int i = blockIdx.x * blockDim.x + threadIdx.x;
  if (i >= total4) return;
  float4 v = ((const float4*)src)[i];
  ushort4 h, l;
  h.x = f2bf(v.x); l.x = f2bf(v.x - bf2f(h.x));
  h.y = f2bf(v.y); l.y = f2bf(v.y - bf2f(h.y));
  h.z = f2bf(v.z); l.z = f2bf(v.z - bf2f(h.z));
  h.w = f2bf(v.w); l.w = f2bf(v.w - bf2f(h.w));
  ((ushort4*)hi)[i] = h;
  ((ushort4*)lo)[i] = l;
}

// W [K][256] f32 -> transposed Wt_hi/lo [256][K] bf16
__global__ void split_wt_kernel(const float* __restrict__ W, int K,
                                unsigned short* __restrict__ hi,
                                unsigned short* __restrict__ lo) {
  int idx = blockIdx.x * blockDim.x + threadIdx.x;
  if (idx >= K * HC) return;
  int k = idx >> 8, c = idx & 255;
  float v = W[idx];
  unsigned short h = f2bf(v);
  hi[c * K + k] = h;
  lo[c * K + k] = f2bf(v - bf2f(h));
}

// ---------------- MFMA bf16-split GEMM (fused segments) ----------------
// Y = X @ W via Xhi*Whi + Xlo*Whi + Xhi*Wlo. All 4 tiles (Ahi/Alo/Bhi/Blo)
// staged ONCE per k-tile; 48 MFMA between one barrier pair. 128x128 tile,
// 4 waves (2x2 of 64x64), 16x16x32 MFMA. quad: 0,1 -> Wl/Yl; 2,3 -> Wr/Yr.
__global__ __launch_bounds__(256, 2) void gemm_mfma_kernel(
    const unsigned short* __restrict__ Ahi, const unsigned short* __restrict__ Alo,
    const unsigned short* __restrict__ Wlhi, const unsigned short* __restrict__ Wllo,
    const unsigned short* __restrict__ Wrhi, const unsigned short* __restrict__ Wrlo,
    float* __restrict__ Yl, float* __restrict__ Yr, int n, int K) {
  __shared__ unsigned short Ah[128][40];   // +8 pad: conflict-free b128 reads
  __shared__ unsigned short Al[128][40];
  __shared__ unsigned short Bh[128][40];
  __shared__ unsigned short Bl[128][40];
  const int t = threadIdx.x;
  const int row0 = blockIdx.x * 128;
  const int quad = blockIdx.y;
  const unsigned short* Bhi = (quad < 2) ? Wlhi : Wrhi;
  const unsigned short* Blo = (quad < 2) ? Wllo : Wrlo;
  float* Y = (quad < 2) ? Yl : Yr;
  const int colbase = (quad & 1) * 128;
  const int l = t & 63, w = t >> 6;
  const int mw = (w >> 1) * 64, nw = (w & 1) * 64;
  const int lr = l & 15, lk = (l >> 4) * 8;
  const int srow = t >> 1, scb = (t & 1) << 4;   // staging: row, col-base

  f32x4 acc[4][4] = {};
  for (int k0 = 0; k0 < K; k0 += 32) {
    // stage all 4 tiles once
    {
      uint4 h0 = {0,0,0,0}, h1 = {0,0,0,0}, l0 = {0,0,0,0}, l1 = {0,0,0,0};
      int r = row0 + srow;
      if (r < n) {
        const uint4* ph = (const uint4*)(Ahi + (size_t)r * K + k0 + scb);
        h0 = ph[0]; h1 = ph[1];
        const uint4* pl = (const uint4*)(Alo + (size_t)r * K + k0 + scb);
        l0 = pl[0]; l1 = pl[1];
      }
      *(uint4*)(&Ah[srow][scb])     = h0;
      *(uint4*)(&Ah[srow][scb + 8]) = h1;
      *(uint4*)(&Al[srow][scb])     = l0;
      *(uint4*)(&Al[srow][scb + 8]) = l1;
    }
    {
      const uint4* ph = (const uint4*)(Bhi + (size_t)(colbase + srow) * K + k0 + scb);
      *(uint4*)(&Bh[srow][scb])     = ph[0];
      *(uint4*)(&Bh[srow][scb + 8]) = ph[1];
      const uint4* pl = (const uint4*)(Blo + (size_t)(colbase + srow) * K + k0 + scb);
      *(uint4*)(&Bl[srow][scb])     = pl[0];
      *(uint4*)(&Bl[srow][scb + 8]) = pl[1];
    }
    __syncthreads();
    bf16x8 ah[4], bb[4], tt[4];
#pragma unroll
    for (int i = 0; i < 4; ++i)
      ah[i] = __builtin_bit_cast(bf16x8, *(const ushort8v*)(&Ah[mw + i * 16 + lr][lk]));
#pragma unroll
    for (int j = 0; j < 4; ++j)
      bb[j] = __builtin_bit_cast(bf16x8, *(const ushort8v*)(&Bh[nw + j * 16 + lr][lk]));
    // ahi * bhi
#pragma unroll
    for (int i = 0; i < 4; ++i)
#pragma unroll
      for (int j = 0; j < 4; ++j)
        acc[i][j] = __builtin_amdgcn_mfma_f32_16x16x32_bf16(ah[i], bb[j], acc[i][j], 0, 0, 0);
    // alo * bhi  (tt = Alo frags)
#pragma unroll
    for (int i = 0; i < 4; ++i)
      tt[i] = __builtin_bit_cast(bf16x8, *(const ushort8v*)(&Al[mw + i * 16 + lr][lk]));
#pragma unroll
    for (int i = 0; i < 4; ++i)
#pragma unroll
      for (int j = 0; j < 4; ++j)
        acc[i][j] = __builtin_amdgcn_mfma_f32_16x16x32_bf16(tt[i], bb[j], acc[i][j], 0, 0, 0);
    // ahi * blo  (tt reused = Blo frags)
#pragma unroll
    for (int j = 0; j < 4; ++j)
      tt[j] = __builtin_bit_cast(bf16x8, *(const ushort8v*)(&Bl[nw + j * 16 + lr][lk]));
#pragma unroll
    for (int i = 0; i < 4; ++i)
#pragma unroll
      for (int j = 0; j < 4; ++j)
        acc[i][j] = __builtin_amdgcn_mfma_f32_16x16x32_bf16(ah[i], tt[j], acc[i][j], 0, 0, 0);
    __syncthreads();
  }
  // epilogue: D frag layout col=lane&15, row=(lane>>4)*4+reg [m89-verified]
#pragma unroll
  for (int i = 0; i < 4; ++i)
#pragma unroll
    for (int j = 0; j < 4; ++j) {
      int colg = colbase + nw + j * 16 + lr;
#pragma unroll
      for (int r = 0; r < 4; ++r) {
        int row = row0 + mw + i * 16 + (l >> 4) * 4 + r;
        if (row < n) Y[(size_t)row * HC + colg] = acc[i][j][r];
      }
    }
}

// ---------------- f32 GEMM (fallback when ws too small) ----------------
__global__ __launch_bounds__(256, 2) void gemm2_kernel(
    const float* __restrict__ X,
    const float* __restrict__ Wl, const float* __restrict__ Wr,
    float* __restrict__ Yl, float* __restrict__ Yr, int n, int K) {
  __shared__ float Xs[16][128];
  __shared__ float Ws[16][128];
  const int tid = threadIdx.x;
  const int row0 = blockIdx.x * 128;
  const int quad = blockIdx.y;
  const float* W = (quad < 2) ? Wl : Wr;
  float* Y = (quad < 2) ? Yl : Yr;
  const int col0 = (quad & 1) * 128;
  const int tr = tid >> 4, tc = tid & 15;
  float acc[8][8] = {};
  for (int k0 = 0; k0 < K; k0 += 16) {
    {
      int m = tid >> 1;
      int kq = (tid & 1) * 8;
      float4 v0 = make_float4(0.f, 0.f, 0.f, 0.f);
      float4 v1 = make_float4(0.f, 0.f, 0.f, 0.f);
      int r = row0 + m;
      if (r < n) {
        v0 = *(const float4*)(X + (size_t)r * K + k0 + kq);
        v1 = *(const float4*)(X + (size_t)r * K + k0 + kq + 4);
      }
      Xs[kq + 0][m] = v0.x; Xs[kq + 1][m] = v0.y;
      Xs[kq + 2][m] = v0.z; Xs[kq + 3][m] = v0.w;
      Xs[kq + 4][m] = v1.x; Xs[kq + 5][m] = v1.y;
      Xs[kq + 6][m] = v1.z; Xs[kq + 7][m] = v1.w;
    }
    {
      int kk = tid >> 4;
      int nq = (tid & 15) * 8;
      float4 w0 = *(const float4*)(W + (size_t)(k0 + kk) * HC + col0 + nq);
      float4 w1 = *(const float4*)(W + (size_t)(k0 + kk) * HC + col0 + nq + 4);
      *(float4*)(&Ws[kk][nq])     = w0;
      *(float4*)(&Ws[kk][nq + 4]) = w1;
    }
    __syncthreads();
#pragma unroll
    for (int k = 0; k < 16; ++k) {
      float a[8], b[8];
      *(float4*)(a)     = *(const float4*)(&Xs[k][tr * 8]);
      *(float4*)(a + 4) = *(const float4*)(&Xs[k][tr * 8 + 4]);
      *(float4*)(b)     = *(const float4*)(&Ws[k][tc * 8]);
      *(float4*)(b + 4) = *(const float4*)(&Ws[k][tc * 8 + 4]);
#pragma unroll
      for (int i = 0; i < 8; ++i)
#pragma unroll
        for (int jj = 0; jj < 8; ++jj) acc[i][jj] += a[i] * b[jj];
    }
    __syncthreads();
  }
#pragma unroll
  for (int i = 0; i < 8; ++i) {
    int r = row0 + tr * 8 + i;
    if (r < n) {
      *(float4*)(Y + (size_t)r * HC + col0 + tc * 8) =
          make_float4(acc[i][0], acc[i][1], acc[i][2], acc[i][3]);
      *(float4*)(Y + (size_t)r * HC + col0 + tc * 8 + 4) =
          make_float4(acc[i][4], acc[i][5], acc[i][6], acc[i][7]);
    }
  }
}

// ---------------- fused edge score + softmax + aggregate (r14, unchanged) --------
template <int B>
__device__ __forceinline__ void edge_batch(
    int j, const int2* __restrict__ edg, const float* __restrict__ xl,
    const float* __restrict__ ea, const v2f (&wreg)[8],
    float see, float xrl, float attl, unsigned c,
    float& den, float& acc) {
  int2 E[B];
#pragma unroll
  for (int k = 0; k < B; ++k) E[k] = edg[(unsigned)(j + k)];
  float X[B];
#pragma unroll
  for (int k = 0; k < B; ++k) X[k] = xl[((unsigned)E[k].y << 8) + c];
  float q[B];
#pragma unroll
  for (int k = 0; k < B; ++k) {
    float ee;
    if (E[k].x < NE) {
      const float* eap = ea + ((size_t)((unsigned)E[k].x << 4));
      v4f a0 = *(const v4f*)(eap);
      v4f a1 = *(const v4f*)(eap + 4);
      v4f a2 = *(const v4f*)(eap + 8);
      v4f a3 = *(const v4f*)(eap + 12);
      v2f s = (v2f){a0.x, a0.y} * wreg[0] + (v2f){a0.z, a0.w} * wreg[1]
            + (v2f){a1.x, a1.y} * wreg[2] + (v2f){a1.z, a1.w} * wreg[3]
            + (v2f){a2.x, a2.y} * wreg[4] + (v2f){a2.z, a2.w} * wreg[5]
            + (v2f){a3.x, a3.y} * wreg[6] + (v2f){a3.z, a3.w} * wreg[7];
      ee = s.x + s.y;
    } else {
      ee = see;
    }
    float t = X[k] + xrl + ee;
    t = fmaxf(t, SLOPE * t);
    q[k] = t * attl;
  }
#pragma unroll
  for (int k = 0; k < B; ++k) q[k] = wave_sum_bcast(q[k]);
#pragma unroll
  for (int k = 0; k < B; ++k) {
    float w = __builtin_amdgcn_exp2f(q[k]);
    den += w;
    acc = fmaf(w, X[k], acc);
  }
}

__global__ __launch_bounds__(256, 4) void edge_agg_kernel(
    const float* __restrict__ xl, const float* __restrict__ xr,
    const int* __restrict__ row_ptr, const int2* __restrict__ edg,
    const float* __restrict__ ea, const float* __restrict__ meanea,
    const float* __restrict__ We, const float* __restrict__ att,
    const float* __restrict__ bias, float* __restrict__ out,
    unsigned short* __restrict__ outhi, unsigned short* __restrict__ outlo) {
  const int lane = threadIdx.x & 63;
  const int head = threadIdx.x >> 6;
  const int node = blockIdx.x;
  const unsigned c = (unsigned)head * CC + (unsigned)lane;

  v2f wreg[8];
#pragma unroll
  for (int d = 0; d < 8; ++d)
    wreg[d] = (v2f){We[(unsigned)(2 * d) * HC + c], We[(unsigned)(2 * d + 1) * HC + c]};
  const float attl = att[c] * 1.44269504088896340736f;
  const float xrl  = xr[((unsigned)node << 8) + c];
  v2f seev = {0.f, 0.f};
#pragma unroll
  for (int d = 0; d < 8; ++d)
    seev += (v2f){meanea[2 * d], meanea[2 * d + 1]} * wreg[d];
  const float see = seev.x + seev.y;

  float den = 0.f, acc = 0.f;
  const int beg = row_ptr[node];
  const int end = row_ptr[node + 1];

  int j = beg;
  for (; j + 8 <= end; j += 8)
    edge_batch<8>(j, edg, xl, ea, wreg, see, xrl, attl, c, den, acc);
  const int rem = end - j;
  if (rem & 4) {
    edge_batch<4>(j, edg, xl, ea, wreg, see, xrl, attl, c, den, acc);
    j += 4;
  }
  if (rem & 2) {
    edge_batch<2>(j, edg, xl, ea, wreg, see, xrl, attl, c, den, acc);
    j += 2;
  }
  if (rem & 1) {
    edge_batch<1>(j, edg, xl, ea, wreg, see, xrl, attl, c, den, acc);
  }

  float o = fmaxf(acc / (den + 1e-16f) + bias[c], 0.f);
  unsigned idx = ((unsigned)node << 8) + c;
  if (outhi) {           // write bf16 split (feeds MFMA GEMM of next layer)
    unsigned short h = f2bf(o);
    outhi[idx] = h;
    outlo[idx] = f2bf(o - bf2f(h));
  } else {
    out[idx] = o;
  }
}

// ---------------- fused global-mean-pool + final linear ----------------
// one wave per graph: lane owns 4 channels; pool sum, dot with Wf slice,
// wave-reduce, write out[g].
__global__ void poolfinal_kernel(const float* __restrict__ h2,
                                 const int* __restrict__ gstart,
                                 const float* __restrict__ Wf,
                                 const float* __restrict__ bf,
                                 float* __restrict__ out) {
  int lane = threadIdx.x & 63;
  int g = blockIdx.x * 4 + (threadIdx.x >> 6);
  if (g >= NG) return;
  int s = RFL(gstart[g]), e = RFL(gstart[g + 1]);
  float sx = 0.f, sy = 0.f, sz = 0.f, sw = 0.f;
  for (int i = s; i < e; ++i) {
    float4 v = *(const float4*)(h2 + (size_t)i * HC + lane * 4);
    sx += v.x; sy += v.y; sz += v.z; sw += v.w;
  }
  float inv = 1.f / fmaxf((float)(e - s), 1.f);
  float4 w = *(const float4*)(Wf + lane * 4);
  float sdot = (sx * w.x + sy * w.y + sz * w.z + sw * w.w) * inv;
  sdot += __shfl_xor(sdot, 1, 64);  sdot += __shfl_xor(sdot, 2, 64);
  sdot += __shfl_xor(sdot, 4, 64);  sdot += __shfl_xor(sdot, 8, 64);
  sdot += __shfl_xor(sdot, 16, 64); sdot += __shfl_xor(sdot, 32, 64);
  if (lane == 0) out[g] = sdot + bf[0];
}

extern "C" void kernel_launch(void* const* d_in, const int* in_sizes, int n_in,
                              void* d_out, int out_size, void* d_ws, size_t ws_size,
                              hipStream_t stream) {
  const float* x    = (const float*)d_in[0];
  const int*   ei   = (const int*)d_in[1];
  const int*   batch= (const int*)d_in[2];
  const float* ea   = (const float*)d_in[3];
  const float* Wl1  = (const float*)d_in[4];
  const float* Wr1  = (const float*)d_in[5];
  const float* We1  = (const float*)d_in[6];
  const float* att1 = (const float*)d_in[7];
  const float* b1   = (const float*)d_in[8];
  const float* Wl2  = (const float*)d_in[9];
  const float* Wr2  = (const float*)d_in[10];
  const float* We2  = (const float*)d_in[11];
  const float* att2 = (const float*)d_in[12];
  const float* b2   = (const float*)d_in[13];
  const float* Wf   = (const float*)d_in[14];
  const float* bf   = (const float*)d_in[15];
  float* out = (float*)d_out;

  // ---- workspace layout (f32, then ints, then bf16/ushort) ----
  float* xl      = (float*)d_ws;               // N*256
  float* xr      = xl + (size_t)NN * HC;       // N*256
  float* h1      = xr + (size_t)NN * HC;       // N*256
  float* meansum = h1 + (size_t)NN * HC;       // 16
  float* meanea  = meansum + 16;               // 16
  int* counts  = (int*)(meanea + 16);          // N
  int* cursor  = counts + NN;                  // N (adjacent: one memset)
  int* row_ptr = cursor + NN;                  // N+1 (+1 pad)
  int* btot    = row_ptr + NN + 2;             // 256
  int* gstart  = btot + 256;                   // G+1 (+1 pad -> edg 8B aligned)
  int2* edg    = (int2*)(gstart + NG + 2);     // E2
  unsigned short* Xhi  = (unsigned short*)(edg + NE2);  // N*64
  unsigned short* Xlo  = Xhi + (size_t)NN * INC;        // N*64
  unsigned short* Hhi  = Xlo + (size_t)NN * INC;        // N*256
  unsigned short* Hlo  = Hhi + (size_t)NN * HC;         // N*256
  unsigned short* Wlh1 = Hlo + (size_t)NN * HC;         // 256*64
  unsigned short* Wll1 = Wlh1 + HC * INC;
  unsigned short* Wrh1 = Wll1 + HC * INC;
  unsigned short* Wrl1 = Wrh1 + HC * INC;
  unsigned short* Wlh2 = Wrl1 + HC * INC;               // 256*256
  unsigned short* Wll2 = Wlh2 + HC * HC;
  unsigned short* Wrh2 = Wll2 + HC * HC;
  unsigned short* Wrl2 = Wrh2 + HC * HC;
  size_t need = (size_t)((char*)(Wrl2 + HC * HC) - (char*)d_ws);
  const bool use_mfma = (ws_size >= need);

  const int NB = (NN + 255) / 256;

  hipMemsetAsync(counts, 0, 2 * NN * sizeof(int), stream);   // counts + cursor
  hipMemsetAsync(meansum, 0, 16 * sizeof(float), stream);

  ea_sum_kernel<<<1024, 256, 0, stream>>>(ea, meansum);

  count_dst_kernel<<<(NE2 + 255) / 256, 256, 0, stream>>>(ei, counts);
  scan_partial_kernel<<<NB, 256, 0, stream>>>(counts, NN, row_ptr, btot);
  scan_btot_kernel<<<1, 256, 0, stream>>>(btot, NB, row_ptr + NN, meansum, meanea);
  scan_add_kernel<<<NB, 256, 0, stream>>>(row_ptr, NN, btot, batch, gstart);
  fill_kernel<<<(NE2 + 255) / 256, 256, 0, stream>>>(ei, row_ptr, cursor, edg);

  if (use_mfma) {
    // split inputs & weights to bf16 hi/lo
    split4_kernel<<<(NN * INC / 4 + 255) / 256, 256, 0, stream>>>(x, Xhi, Xlo, NN * INC / 4);
    split_wt_kernel<<<(INC * HC + 255) / 256, 256, 0, stream>>>(Wl1, INC, Wlh1, Wll1);
    split_wt_kernel<<<(INC * HC + 255) / 256, 256, 0, stream>>>(Wr1, INC, Wrh1, Wrl1);
    split_wt_kernel<<<(HC * HC + 255) / 256, 256, 0, stream>>>(Wl2, HC, Wlh2, Wll2);
    split_wt_kernel<<<(HC * HC + 255) / 256, 256, 0, stream>>>(Wr2, HC, Wrh2, Wrl2);

    dim3 mgrid((NN + 127) / 128, 4);
    // layer 1: [xl|xr] = x @ [Wl1|Wr1] via fused 3-product bf16 MFMA
    gemm_mfma_kernel<<<mgrid, 256, 0, stream>>>(Xhi, Xlo, Wlh1, Wll1, Wrh1, Wrl1,
                                                xl, xr, NN, INC);
    // edge_agg L1 writes bf16 split directly (feeds L2 GEMM)
    edge_agg_kernel<<<NN, 256, 0, stream>>>(xl, xr, row_ptr, edg, ea, meanea,
                                            We1, att1, b1, nullptr, Hhi, Hlo);
    // layer 2
    gemm_mfma_kernel<<<mgrid, 256, 0, stream>>>(Hhi, Hlo, Wlh2, Wll2, Wrh2, Wrl2,
                                                xl, xr, NN, HC);
    edge_agg_kernel<<<NN, 256, 0, stream>>>(xl, xr, row_ptr, edg, ea, meanea,
                                            We2, att2, b2, h1, nullptr, nullptr);
  } else {
    // fallback: proven f32 path (r14)
    dim3 ggrid((NN + 127) / 128, 4);
    gemm2_kernel<<<ggrid, 256, 0, stream>>>(x, Wl1, Wr1, xl, xr, NN, INC);
    edge_agg_kernel<<<NN, 256, 0, stream>>>(xl, xr, row_ptr, edg, ea, meanea,
                                            We1, att1, b1, h1, nullptr, nullptr);
    gemm2_kernel<<<ggrid, 256, 0, stream>>>(h1, Wl2, Wr2, xl, xr, NN, HC);
    edge_agg_kernel<<<NN, 256, 0, stream>>>(xl, xr, row_ptr, edg, ea, meanea,
                                            We2, att2, b2, h1, nullptr, nullptr);
  }

  // fused pooling + ffn
  poolfinal_kernel<<<(NG + 3) / 4, 256, 0, stream>>>(h1, gstart, Wf, bf, out);
}

// Round 17
// 783.727 us; speedup vs baseline: 1.7716x; 1.0199x over previous
//
#include <hip/hip_runtime.h>
#include <math.h>

// Problem constants (fixed by the reference)
#define NN 50000          // nodes
#define NE 800000         // edges
#define NE2 (NE + NN)     // edges + self loops = 850000
#define INC 64            // in channels
#define EDD 16            // edge dim
#define NH 4              // heads
#define CC 64             // per-head channels
#define HC 256            // H*C
#define NG 2048           // graphs
#define SLOPE 0.2f

typedef float v2f __attribute__((ext_vector_type(2)));
typedef float v4f __attribute__((ext_vector_type(4)));
typedef __bf16 bf16x8 __attribute__((ext_vector_type(8)));
typedef float f32x4 __attribute__((ext_vector_type(4)));
typedef unsigned short ushort8v __attribute__((ext_vector_type(8)));

#define RFL(x) __builtin_amdgcn_readfirstlane(x)

// f32 -> bf16 (rne) and back
__device__ __forceinline__ unsigned short f2bf(float f) {
  unsigned u = __builtin_bit_cast(unsigned, f);
  u += 0x7FFF + ((u >> 16) & 1);
  return (unsigned short)(u >> 16);
}
__device__ __forceinline__ float bf2f(unsigned short h) {
  return __builtin_bit_cast(float, ((unsigned)h) << 16);
}

// ---------------- DPP wave-64 sum (VALU pipe, no DS traffic) ----------------
template <int CTRL, int RM>
__device__ __forceinline__ float dpp_add(float x) {
  int t = __builtin_amdgcn_update_dpp(0, __builtin_bit_cast(int, x),
                                      CTRL, RM, 0xF, false);
  return x + __builtin_bit_cast(float, t);
}
__device__ __forceinline__ float wave_sum_bcast(float x) {
  x = dpp_add<0x111, 0xF>(x);   // row_shr:1
  x = dpp_add<0x112, 0xF>(x);   // row_shr:2
  x = dpp_add<0x114, 0xF>(x);   // row_shr:4
  x = dpp_add<0x118, 0xF>(x);   // row_shr:8
  x = dpp_add<0x142, 0xA>(x);   // row_bcast:15
  x = dpp_add<0x143, 0xC>(x);   // row_bcast:31 -> lane63 = full sum
  return __builtin_bit_cast(float,
      __builtin_amdgcn_readlane(__builtin_bit_cast(int, x), 63));
}

// ---------------- mean edge attr ----------------
__global__ void ea_sum_kernel(const float* __restrict__ ea, float* __restrict__ meansum) {
  __shared__ float part[16];
  if (threadIdx.x < 16) part[threadIdx.x] = 0.f;
  __syncthreads();
  size_t stride = (size_t)gridDim.x * blockDim.x;
  size_t i = (size_t)blockIdx.x * blockDim.x + threadIdx.x;
  int cls = (int)(i & 15);
  float s = 0.f;
  const size_t total = (size_t)NE * EDD;
  for (; i < total; i += stride) s += ea[i];
  atomicAdd(&part[cls], s);
  __syncthreads();
  if (threadIdx.x < 16) atomicAdd(&meansum[threadIdx.x], part[threadIdx.x]);
}

// ---------------- CSR build ----------------
__global__ void count_dst_kernel(const int* __restrict__ ei, int* __restrict__ counts) {
  int e = blockIdx.x * blockDim.x + threadIdx.x;
  if (e >= NE2) return;
  int d = (e < NE) ? ei[NE + e] : (e - NE);
  atomicAdd(&counts[d], 1);
}

__global__ void scan_partial_kernel(const int* __restrict__ counts, int n,
                                    int* __restrict__ excl, int* __restrict__ btot) {
  int b = blockIdx.x;
  int i = b * 256 + threadIdx.x;
  int v = (i < n) ? counts[i] : 0;
  int lane = threadIdx.x & 63;
  int incl = v;
#pragma unroll
  for (int off = 1; off < 64; off <<= 1) {
    int t = __shfl_up(incl, off, 64);
    if (lane >= off) incl += t;
  }
  __shared__ int wtot[4];
  int w = threadIdx.x >> 6;
  if (lane == 63) wtot[w] = incl;
  __syncthreads();
  int woff = 0;
#pragma unroll
  for (int k = 0; k < 4; ++k) woff += (k < w) ? wtot[k] : 0;
  incl += woff;
  if (i < n) excl[i] = incl - v;
  if (threadIdx.x == 255) btot[b] = incl;
}

__global__ void scan_btot_kernel(int* __restrict__ btot, int nb, int* __restrict__ totp,
                                 const float* __restrict__ meansum,
                                 float* __restrict__ meanea) {
  __shared__ int buf[256];
  int v = (threadIdx.x < nb) ? btot[threadIdx.x] : 0;
  buf[threadIdx.x] = v;
  __syncthreads();
  for (int off = 1; off < 256; off <<= 1) {
    int t = (threadIdx.x >= off) ? buf[threadIdx.x - off] : 0;
    __syncthreads();
    buf[threadIdx.x] += t;
    __syncthreads();
  }
  if (threadIdx.x < nb) btot[threadIdx.x] = buf[threadIdx.x] - v;
  if (threadIdx.x == 0) *totp = buf[nb - 1];
  if (threadIdx.x < 16) meanea[threadIdx.x] = meansum[threadIdx.x] * (1.0f / NE);
}

__global__ void scan_add_kernel(int* __restrict__ excl, int n, const int* __restrict__ btot,
                                const int* __restrict__ batch, int* __restrict__ gstart) {
  int i = blockIdx.x * 256 + threadIdx.x;
  if (i < n) excl[i] += btot[blockIdx.x];
  if (i < NN) {
    int b = batch[i];
    int prev = (i == 0) ? -1 : batch[i - 1];
    for (int g = prev + 1; g <= b; ++g) gstart[g] = i;
    if (i == NN - 1)
      for (int g = b + 1; g <= NG; ++g) gstart[g] = NN;
  }
}

// edge record pre-scaled: x = e*EDD (element offset into ea) or INT_MAX for
// self-loops; y = src*HC (element offset into xl).
__global__ void fill_kernel(const int* __restrict__ ei, const int* __restrict__ row_ptr,
                            int* __restrict__ cursor, int2* __restrict__ edg) {
  int e = blockIdx.x * blockDim.x + threadIdx.x;
  if (e >= NE2) return;
  int d, s, eo;
  if (e < NE) { d = ei[NE + e]; s = ei[e]; eo = e * EDD; }
  else        { d = e - NE;     s = d;     eo = 0x7fffffff; }
  int pos = row_ptr[d] + atomicAdd(&cursor[d], 1);
  edg[pos] = make_int2(eo, s * HC);
}

// ---------------- bf16 split: all 4 weight matrices in one dispatch ----------------
__global__ void split_wt_all_kernel(
    const float* __restrict__ Wl1, const float* __restrict__ Wr1,
    const float* __restrict__ Wl2, const float* __restrict__ Wr2,
    unsigned short* __restrict__ Wlh1, unsigned short* __restrict__ Wll1,
    unsigned short* __restrict__ Wrh1, unsigned short* __restrict__ Wrl1,
    unsigned short* __restrict__ Wlh2, unsigned short* __restrict__ Wll2,
    unsigned short* __restrict__ Wrh2, unsigned short* __restrict__ Wrl2) {
  const int S1 = INC * HC;       // 16384
  const int S2 = HC * HC;        // 65536
  int idx = blockIdx.x * blockDim.x + threadIdx.x;
  const float* W; unsigned short *hi, *lo; int K, off;
  if (idx < S1)                { W = Wl1; hi = Wlh1; lo = Wll1; K = INC; off = idx; }
  else if (idx < 2 * S1)       { W = Wr1; hi = Wrh1; lo = Wrl1; K = INC; off = idx - S1; }
  else if (idx < 2 * S1 + S2)  { W = Wl2; hi = Wlh2; lo = Wll2; K = HC;  off = idx - 2 * S1; }
  else if (idx < 2 * S1 + 2 * S2) { W = Wr2; hi = Wrh2; lo = Wrl2; K = HC; off = idx - 2 * S1 - S2; }
  else return;
  int k = off >> 8, c = off & 255;
  float v = W[(size_t)k * HC + c];
  unsigned short h = f2bf(v);
  hi[c * K + k] = h;                 // transposed [256][K]
  lo[c * K + k] = f2bf(v - bf2f(h));
}

// ---------------- MFMA bf16-split GEMM (fused segments) ----------------
// Y = X @ W via Xhi*Whi + Xlo*Whi + Xhi*Wlo. All 4 tiles staged once per
// k-tile; 48 MFMA between one barrier pair. AF32: A is f32, split during
// staging (saves the separate split pass for layer 1).
template <bool AF32>
__global__ __launch_bounds__(256, 2) void gemm_mfma_kernel(
    const float* __restrict__ Af,
    const unsigned short* __restrict__ Ahi, const unsigned short* __restrict__ Alo,
    const unsigned short* __restrict__ Wlhi, const unsigned short* __restrict__ Wllo,
    const unsigned short* __restrict__ Wrhi, const unsigned short* __restrict__ Wrlo,
    float* __restrict__ Yl, float* __restrict__ Yr, int n, int K) {
  __shared__ unsigned short Ah[128][40];   // +8 pad: conflict-free b128 reads
  __shared__ unsigned short Al[128][40];
  __shared__ unsigned short Bh[128][40];
  __shared__ unsigned short Bl[128][40];
  const int t = threadIdx.x;
  const int row0 = blockIdx.x * 128;
  const int quad = blockIdx.y;
  const unsigned short* Bhi = (quad < 2) ? Wlhi : Wrhi;
  const unsigned short* Blo = (quad < 2) ? Wllo : Wrlo;
  float* Y = (quad < 2) ? Yl : Yr;
  const int colbase = (quad & 1) * 128;
  const int l = t & 63, w = t >> 6;
  const int mw = (w >> 1) * 64, nw = (w & 1) * 64;
  const int lr = l & 15, lk = (l >> 4) * 8;
  const int srow = t >> 1, scb = (t & 1) << 4;   // staging: row, col-base

  f32x4 acc[4][4] = {};
  for (int k0 = 0; k0 < K; k0 += 32) {
    // stage A (hi+lo) once
    if (AF32) {
      float fv[16] = {};
      int r = row0 + srow;
      if (r < n) {
        const float4* p = (const float4*)(Af + (size_t)r * K + k0 + scb);
        *(float4*)(fv)      = p[0];
        *(float4*)(fv + 4)  = p[1];
        *(float4*)(fv + 8)  = p[2];
        *(float4*)(fv + 12) = p[3];
      }
      unsigned short hv[16], lv[16];
#pragma unroll
      for (int q = 0; q < 16; ++q) {
        hv[q] = f2bf(fv[q]);
        lv[q] = f2bf(fv[q] - bf2f(hv[q]));
      }
      *(uint4*)(&Ah[srow][scb])     = *(const uint4*)(hv);
      *(uint4*)(&Ah[srow][scb + 8]) = *(const uint4*)(hv + 8);
      *(uint4*)(&Al[srow][scb])     = *(const uint4*)(lv);
      *(uint4*)(&Al[srow][scb + 8]) = *(const uint4*)(lv + 8);
    } else {
      uint4 h0 = {0,0,0,0}, h1 = {0,0,0,0}, l0 = {0,0,0,0}, l1 = {0,0,0,0};
      int r = row0 + srow;
      if (r < n) {
        const uint4* ph = (const uint4*)(Ahi + (size_t)r * K + k0 + scb);
        h0 = ph[0]; h1 = ph[1];
        const uint4* pl = (const uint4*)(Alo + (size_t)r * K + k0 + scb);
        l0 = pl[0]; l1 = pl[1];
      }
      *(uint4*)(&Ah[srow][scb])     = h0;
      *(uint4*)(&Ah[srow][scb + 8]) = h1;
      *(uint4*)(&Al[srow][scb])     = l0;
      *(uint4*)(&Al[srow][scb + 8]) = l1;
    }
    // stage B (hi+lo)
    {
      const uint4* ph = (const uint4*)(Bhi + (size_t)(colbase + srow) * K + k0 + scb);
      *(uint4*)(&Bh[srow][scb])     = ph[0];
      *(uint4*)(&Bh[srow][scb + 8]) = ph[1];
      const uint4* pl = (const uint4*)(Blo + (size_t)(colbase + srow) * K + k0 + scb);
      *(uint4*)(&Bl[srow][scb])     = pl[0];
      *(uint4*)(&Bl[srow][scb + 8]) = pl[1];
    }
    __syncthreads();
    bf16x8 ah[4], bb[4], tt[4];
#pragma unroll
    for (int i = 0; i < 4; ++i)
      ah[i] = __builtin_bit_cast(bf16x8, *(const ushort8v*)(&Ah[mw + i * 16 + lr][lk]));
#pragma unroll
    for (int j = 0; j < 4; ++j)
      bb[j] = __builtin_bit_cast(bf16x8, *(const ushort8v*)(&Bh[nw + j * 16 + lr][lk]));
    // ahi * bhi
#pragma unroll
    for (int i = 0; i < 4; ++i)
#pragma unroll
      for (int j = 0; j < 4; ++j)
        acc[i][j] = __builtin_amdgcn_mfma_f32_16x16x32_bf16(ah[i], bb[j], acc[i][j], 0, 0, 0);
    // alo * bhi
#pragma unroll
    for (int i = 0; i < 4; ++i)
      tt[i] = __builtin_bit_cast(bf16x8, *(const ushort8v*)(&Al[mw + i * 16 + lr][lk]));
#pragma unroll
    for (int i = 0; i < 4; ++i)
#pragma unroll
      for (int j = 0; j < 4; ++j)
        acc[i][j] = __builtin_amdgcn_mfma_f32_16x16x32_bf16(tt[i], bb[j], acc[i][j], 0, 0, 0);
    // ahi * blo
#pragma unroll
    for (int j = 0; j < 4; ++j)
      tt[j] = __builtin_bit_cast(bf16x8, *(const ushort8v*)(&Bl[nw + j * 16 + lr][lk]));
#pragma unroll
    for (int i = 0; i < 4; ++i)
#pragma unroll
      for (int j = 0; j < 4; ++j)
        acc[i][j] = __builtin_amdgcn_mfma_f32_16x16x32_bf16(ah[i], tt[j], acc[i][j], 0, 0, 0);
    __syncthreads();
  }
  // epilogue: D frag layout col=lane&15, row=(lane>>4)*4+reg [m89-verified]
#pragma unroll
  for (int i = 0; i < 4; ++i)
#pragma unroll
    for (int j = 0; j < 4; ++j) {
      int colg = colbase + nw + j * 16 + lr;
#pragma unroll
      for (int r = 0; r < 4; ++r) {
        int row = row0 + mw + i * 16 + (l >> 4) * 4 + r;
        if (row < n) Y[(size_t)row * HC + colg] = acc[i][j][r];
      }
    }
}

// ---------------- f32 GEMM (fallback when ws too small) ----------------
__global__ __launch_bounds__(256, 2) void gemm2_kernel(
    const float* __restrict__ X,
    const float* __restrict__ Wl, const float* __restrict__ Wr,
    float* __restrict__ Yl, float* __restrict__ Yr, int n, int K) {
  __shared__ float Xs[16][128];
  __shared__ float Ws[16][128];
  const int tid = threadIdx.x;
  const int row0 = blockIdx.x * 128;
  const int quad = blockIdx.y;
  const float* W = (quad < 2) ? Wl : Wr;
  float* Y = (quad < 2) ? Yl : Yr;
  const int col0 = (quad & 1) * 128;
  const int tr = tid >> 4, tc = tid & 15;
  float acc[8][8] = {};
  for (int k0 = 0; k0 < K; k0 += 16) {
    {
      int m = tid >> 1;
      int kq = (tid & 1) * 8;
      float4 v0 = make_float4(0.f, 0.f, 0.f, 0.f);
      float4 v1 = make_float4(0.f, 0.f, 0.f, 0.f);
      int r = row0 + m;
      if (r < n) {
        v0 = *(const float4*)(X + (size_t)r * K + k0 + kq);
        v1 = *(const float4*)(X + (size_t)r * K + k0 + kq + 4);
      }
      Xs[kq + 0][m] = v0.x; Xs[kq + 1][m] = v0.y;
      Xs[kq + 2][m] = v0.z; Xs[kq + 3][m] = v0.w;
      Xs[kq + 4][m] = v1.x; Xs[kq + 5][m] = v1.y;
      Xs[kq + 6][m] = v1.z; Xs[kq + 7][m] = v1.w;
    }
    {
      int kk = tid >> 4;
      int nq = (tid & 15) * 8;
      float4 w0 = *(const float4*)(W + (size_t)(k0 + kk) * HC + col0 + nq);
      float4 w1 = *(const float4*)(W + (size_t)(k0 + kk) * HC + col0 + nq + 4);
      *(float4*)(&Ws[kk][nq])     = w0;
      *(float4*)(&Ws[kk][nq + 4]) = w1;
    }
    __syncthreads();
#pragma unroll
    for (int k = 0; k < 16; ++k) {
      float a[8], b[8];
      *(float4*)(a)     = *(const float4*)(&Xs[k][tr * 8]);
      *(float4*)(a + 4) = *(const float4*)(&Xs[k][tr * 8 + 4]);
      *(float4*)(b)     = *(const float4*)(&Ws[k][tc * 8]);
      *(float4*)(b + 4) = *(const float4*)(&Ws[k][tc * 8 + 4]);
#pragma unroll
      for (int i = 0; i < 8; ++i)
#pragma unroll
        for (int jj = 0; jj < 8; ++jj) acc[i][jj] += a[i] * b[jj];
    }
    __syncthreads();
  }
#pragma unroll
  for (int i = 0; i < 8; ++i) {
    int r = row0 + tr * 8 + i;
    if (r < n) {
      *(float4*)(Y + (size_t)r * HC + col0 + tc * 8) =
          make_float4(acc[i][0], acc[i][1], acc[i][2], acc[i][3]);
      *(float4*)(Y + (size_t)r * HC + col0 + tc * 8 + 4) =
          make_float4(acc[i][4], acc[i][5], acc[i][6], acc[i][7]);
    }
  }
}

// ---------------- fused edge score + softmax + aggregate ----------------
// r14 structure; edge records now pre-scaled (no shifts in the hot loop).
template <int B>
__device__ __forceinline__ void edge_batch(
    int j, const int2* __restrict__ edg, const float* __restrict__ xl,
    const float* __restrict__ ea, const v2f (&wreg)[8],
    float see, float xrl, float attl, unsigned c,
    float& den, float& acc) {
  int2 E[B];
#pragma unroll
  for (int k = 0; k < B; ++k) E[k] = edg[(unsigned)(j + k)];
  float X[B];
#pragma unroll
  for (int k = 0; k < B; ++k) X[k] = xl[(unsigned)E[k].y + c];
  float q[B];
#pragma unroll
  for (int k = 0; k < B; ++k) {
    float ee;
    if (E[k].x < NE * EDD) {          // sentinel INT_MAX fails this
      const float* eap = ea + (unsigned)E[k].x;
      v4f a0 = *(const v4f*)(eap);
      v4f a1 = *(const v4f*)(eap + 4);
      v4f a2 = *(const v4f*)(eap + 8);
      v4f a3 = *(const v4f*)(eap + 12);
      v2f s = (v2f){a0.x, a0.y} * wreg[0] + (v2f){a0.z, a0.w} * wreg[1]
            + (v2f){a1.x, a1.y} * wreg[2] + (v2f){a1.z, a1.w} * wreg[3]
            + (v2f){a2.x, a2.y} * wreg[4] + (v2f){a2.z, a2.w} * wreg[5]
            + (v2f){a3.x, a3.y} * wreg[6] + (v2f){a3.z, a3.w} * wreg[7];
      ee = s.x + s.y;
    } else {
      ee = see;
    }
    float t = X[k] + xrl + ee;
    t = fmaxf(t, SLOPE * t);
    q[k] = t * attl;
  }
#pragma unroll
  for (int k = 0; k < B; ++k) q[k] = wave_sum_bcast(q[k]);
#pragma unroll
  for (int k = 0; k < B; ++k) {
    float w = __builtin_amdgcn_exp2f(q[k]);
    den += w;
    acc = fmaf(w, X[k], acc);
  }
}

__global__ __launch_bounds__(256, 4) void edge_agg_kernel(
    const float* __restrict__ xl, const float* __restrict__ xr,
    const int* __restrict__ row_ptr, const int2* __restrict__ edg,
    const float* __restrict__ ea, const float* __restrict__ meanea,
    const float* __restrict__ We, const float* __restrict__ att,
    const float* __restrict__ bias, float* __restrict__ out,
    unsigned short* __restrict__ outhi, unsigned short* __restrict__ outlo) {
  const int lane = threadIdx.x & 63;
  const int head = threadIdx.x >> 6;
  const int node = blockIdx.x;
  const unsigned c = (unsigned)head * CC + (unsigned)lane;

  v2f wreg[8];
#pragma unroll
  for (int d = 0; d < 8; ++d)
    wreg[d] = (v2f){We[(unsigned)(2 * d) * HC + c], We[(unsigned)(2 * d + 1) * HC + c]};
  const float attl = att[c] * 1.44269504088896340736f;
  const float xrl  = xr[((unsigned)node << 8) + c];
  v2f seev = {0.f, 0.f};
#pragma unroll
  for (int d = 0; d < 8; ++d)
    seev += (v2f){meanea[2 * d], meanea[2 * d + 1]} * wreg[d];
  const float see = seev.x + seev.y;

  float den = 0.f, acc = 0.f;
  const int beg = row_ptr[node];
  const int end = row_ptr[node + 1];

  int j = beg;
  for (; j + 8 <= end; j += 8)
    edge_batch<8>(j, edg, xl, ea, wreg, see, xrl, attl, c, den, acc);
  const int rem = end - j;
  if (rem & 4) {
    edge_batch<4>(j, edg, xl, ea, wreg, see, xrl, attl, c, den, acc);
    j += 4;
  }
  if (rem & 2) {
    edge_batch<2>(j, edg, xl, ea, wreg, see, xrl, attl, c, den, acc);
    j += 2;
  }
  if (rem & 1) {
    edge_batch<1>(j, edg, xl, ea, wreg, see, xrl, attl, c, den, acc);
  }

  float o = fmaxf(acc / (den + 1e-16f) + bias[c], 0.f);
  unsigned idx = ((unsigned)node << 8) + c;
  if (outhi) {           // write bf16 split (feeds MFMA GEMM of next layer)
    unsigned short h = f2bf(o);
    outhi[idx] = h;
    outlo[idx] = f2bf(o - bf2f(h));
  } else {
    out[idx] = o;
  }
}

// ---------------- fused global-mean-pool + final linear ----------------
__global__ void poolfinal_kernel(const float* __restrict__ h2,
                                 const int* __restrict__ gstart,
                                 const float* __restrict__ Wf,
                                 const float* __restrict__ bf,
                                 float* __restrict__ out) {
  int lane = threadIdx.x & 63;
  int g = blockIdx.x * 4 + (threadIdx.x >> 6);
  if (g >= NG) return;
  int s = RFL(gstart[g]), e = RFL(gstart[g + 1]);
  float sx = 0.f, sy = 0.f, sz = 0.f, sw = 0.f;
  for (int i = s; i < e; ++i) {
    float4 v = *(const float4*)(h2 + (size_t)i * HC + lane * 4);
    sx += v.x; sy += v.y; sz += v.z; sw += v.w;
  }
  float inv = 1.f / fmaxf((float)(e - s), 1.f);
  float4 w = *(const float4*)(Wf + lane * 4);
  float sdot = (sx * w.x + sy * w.y + sz * w.z + sw * w.w) * inv;
  sdot += __shfl_xor(sdot, 1, 64);  sdot += __shfl_xor(sdot, 2, 64);
  sdot += __shfl_xor(sdot, 4, 64);  sdot += __shfl_xor(sdot, 8, 64);
  sdot += __shfl_xor(sdot, 16, 64); sdot += __shfl_xor(sdot, 32, 64);
  if (lane == 0) out[g] = sdot + bf[0];
}

extern "C" void kernel_launch(void* const* d_in, const int* in_sizes, int n_in,
                              void* d_out, int out_size, void* d_ws, size_t ws_size,
                              hipStream_t stream) {
  const float* x    = (const float*)d_in[0];
  const int*   ei   = (const int*)d_in[1];
  const int*   batch= (const int*)d_in[2];
  const float* ea   = (const float*)d_in[3];
  const float* Wl1  = (const float*)d_in[4];
  const float* Wr1  = (const float*)d_in[5];
  const float* We1  = (const float*)d_in[6];
  const float* att1 = (const float*)d_in[7];
  const float* b1   = (const float*)d_in[8];
  const float* Wl2  = (const float*)d_in[9];
  const float* Wr2  = (const float*)d_in[10];
  const float* We2  = (const float*)d_in[11];
  const float* att2 = (const float*)d_in[12];
  const float* b2   = (const float*)d_in[13];
  const float* Wf   = (const float*)d_in[14];
  const float* bf   = (const float*)d_in[15];
  float* out = (float*)d_out;

  // ---- workspace layout (f32, then ints, then bf16/ushort) ----
  float* xl      = (float*)d_ws;               // N*256
  float* xr      = xl + (size_t)NN * HC;       // N*256
  float* h1      = xr + (size_t)NN * HC;       // N*256
  float* meansum = h1 + (size_t)NN * HC;       // 16
  float* meanea  = meansum + 16;               // 16
  int* counts  = (int*)(meanea + 16);          // N
  int* cursor  = counts + NN;                  // N (adjacent: one memset)
  int* row_ptr = cursor + NN;                  // N+1 (+1 pad)
  int* btot    = row_ptr + NN + 2;             // 256
  int* gstart  = btot + 256;                   // G+1 (+1 pad -> edg 8B aligned)
  int2* edg    = (int2*)(gstart + NG + 2);     // E2
  unsigned short* Hhi  = (unsigned short*)(edg + NE2);  // N*256
  unsigned short* Hlo  = Hhi + (size_t)NN * HC;         // N*256
  unsigned short* Wlh1 = Hlo + (size_t)NN * HC;         // 256*64
  unsigned short* Wll1 = Wlh1 + HC * INC;
  unsigned short* Wrh1 = Wll1 + HC * INC;
  unsigned short* Wrl1 = Wrh1 + HC * INC;
  unsigned short* Wlh2 = Wrl1 + HC * INC;               // 256*256
  unsigned short* Wll2 = Wlh2 + HC * HC;
  unsigned short* Wrh2 = Wll2 + HC * HC;
  unsigned short* Wrl2 = Wrh2 + HC * HC;
  size_t need = (size_t)((char*)(Wrl2 + HC * HC) - (char*)d_ws);
  const bool use_mfma = (ws_size >= need);

  const int NB = (NN + 255) / 256;

  hipMemsetAsync(counts, 0, 2 * NN * sizeof(int), stream);   // counts + cursor
  hipMemsetAsync(meansum, 0, 16 * sizeof(float), stream);

  ea_sum_kernel<<<1024, 256, 0, stream>>>(ea, meansum);

  count_dst_kernel<<<(NE2 + 255) / 256, 256, 0, stream>>>(ei, counts);
  scan_partial_kernel<<<NB, 256, 0, stream>>>(counts, NN, row_ptr, btot);
  scan_btot_kernel<<<1, 256, 0, stream>>>(btot, NB, row_ptr + NN, meansum, meanea);
  scan_add_kernel<<<NB, 256, 0, stream>>>(row_ptr, NN, btot, batch, gstart);
  fill_kernel<<<(NE2 + 255) / 256, 256, 0, stream>>>(ei, row_ptr, cursor, edg);

  if (use_mfma) {
    // split all 4 weights to transposed bf16 hi/lo (one dispatch)
    const int WTOT = 2 * INC * HC + 2 * HC * HC;
    split_wt_all_kernel<<<(WTOT + 255) / 256, 256, 0, stream>>>(
        Wl1, Wr1, Wl2, Wr2, Wlh1, Wll1, Wrh1, Wrl1, Wlh2, Wll2, Wrh2, Wrl2);

    dim3 mgrid((NN + 127) / 128, 4);
    // layer 1: A = x (f32), split during staging
    gemm_mfma_kernel<true><<<mgrid, 256, 0, stream>>>(
        x, nullptr, nullptr, Wlh1, Wll1, Wrh1, Wrl1, xl, xr, NN, INC);
    // edge_agg L1 writes bf16 split directly (feeds L2 GEMM)
    edge_agg_kernel<<<NN, 256, 0, stream>>>(xl, xr, row_ptr, edg, ea, meanea,
                                            We1, att1, b1, nullptr, Hhi, Hlo);
    // layer 2: A = Hhi/Hlo (pre-split)
    gemm_mfma_kernel<false><<<mgrid, 256, 0, stream>>>(
        nullptr, Hhi, Hlo, Wlh2, Wll2, Wrh2, Wrl2, xl, xr, NN, HC);
    edge_agg_kernel<<<NN, 256, 0, stream>>>(xl, xr, row_ptr, edg, ea, meanea,
                                            We2, att2, b2, h1, nullptr, nullptr);
  } else {
    // fallback: proven f32 path (r14)
    dim3 ggrid((NN + 127) / 128, 4);
    gemm2_kernel<<<ggrid, 256, 0, stream>>>(x, Wl1, Wr1, xl, xr, NN, INC);
    edge_agg_kernel<<<NN, 256, 0, stream>>>(xl, xr, row_ptr, edg, ea, meanea,
                                            We1, att1, b1, h1, nullptr, nullptr);
    gemm2_kernel<<<ggrid, 256, 0, stream>>>(h1, Wl2, Wr2, xl, xr, NN, HC);
    edge_agg_kernel<<<NN, 256, 0, stream>>>(xl, xr, row_ptr, edg, ea, meanea,
                                            We2, att2, b2, h1, nullptr, nullptr);
  }

  // fused pooling + ffn
  poolfinal_kernel<<<(NG + 3) / 4, 256, 0, stream>>>(h1, gstart, Wf, bf, out);
}